// Round 5
// baseline (262.449 us; speedup 1.0000x reference)
//
#include <hip/hip_runtime.h>
#include <hip/hip_bf16.h>
#include <cstdint>
#include <cstddef>

// B=4, S=2048, D=1024, H=16, DH=64, M = B*S = 8192
#define S_ 2048
#define D_ 1024
#define H_ 16
#define DH_ 64
#define M_ 8192

using bf16 = __bf16;
using bf16x4 = __attribute__((ext_vector_type(4))) __bf16;
using bf16x8 = __attribute__((ext_vector_type(8))) __bf16;
using f32x4 = __attribute__((ext_vector_type(4))) float;
using s16x4 = __attribute__((ext_vector_type(4))) short;

__device__ __forceinline__ void g2lds16(const bf16* g, bf16* l) {
  __builtin_amdgcn_global_load_lds(
      (const __attribute__((address_space(1))) void*)g,
      (__attribute__((address_space(3))) void*)l, 16, 0, 0);
}

// 16x16x16 bf16 MFMA (used by attn PV)
__device__ __forceinline__ f32x4 mfma16(bf16x4 a, bf16x4 b, f32x4 c) {
#if __has_builtin(__builtin_amdgcn_mfma_f32_16x16x16_bf16)
  return __builtin_amdgcn_mfma_f32_16x16x16_bf16(a, b, c, 0, 0, 0);
#elif __has_builtin(__builtin_amdgcn_mfma_f32_16x16x16bf16_1k)
  return __builtin_amdgcn_mfma_f32_16x16x16bf16_1k(
      __builtin_bit_cast(s16x4, a), __builtin_bit_cast(s16x4, b), c, 0, 0, 0);
#else
  f32x4 d;
  asm("v_mfma_f32_16x16x16_bf16 %0, %1, %2, %3"
      : "=v"(d)
      : "v"(a), "v"(b), "v"(c));
  return d;
#endif
}

// ------- fused fp32->bf16 converts: x (blocks 0..4095) + 4 weights^T -------
__global__ __launch_bounds__(256) void cvt_all_kernel(
    const float* __restrict__ x, const float* __restrict__ w0,
    const float* __restrict__ w1, const float* __restrict__ w2,
    const float* __restrict__ w3, bf16* __restrict__ xb,
    bf16* __restrict__ o0, bf16* __restrict__ o1, bf16* __restrict__ o2,
    bf16* __restrict__ o3) {
  __shared__ float tile[32][33];
  int bx = blockIdx.x;
  int tid = threadIdx.x;
  if (bx < 4096) {
    size_t i = ((size_t)bx * 256 + tid) * 8;
    float4 a = *(const float4*)(x + i);
    float4 b = *(const float4*)(x + i + 4);
    bf16x8 o;
    o[0] = (bf16)a.x; o[1] = (bf16)a.y; o[2] = (bf16)a.z; o[3] = (bf16)a.w;
    o[4] = (bf16)b.x; o[5] = (bf16)b.y; o[6] = (bf16)b.z; o[7] = (bf16)b.w;
    *(bf16x8*)(xb + i) = o;
    return;
  }
  int wb = bx - 4096;
  int wsel = wb >> 10; wb &= 1023;
  const float* W; bf16* O;
  switch (wsel) {
    case 0: W = w0; O = o0; break;
    case 1: W = w1; O = o1; break;
    case 2: W = w2; O = o2; break;
    default: W = w3; O = o3; break;
  }
  int n0 = (wb & 31) * 32;
  int k0 = (wb >> 5) * 32;
#pragma unroll
  for (int i = 0; i < 4; ++i) {
    int e = tid + i * 256; int rr = e >> 5, cc = e & 31;
    tile[rr][cc] = W[(size_t)(k0 + rr) * 1024 + n0 + cc];
  }
  __syncthreads();
#pragma unroll
  for (int i = 0; i < 4; ++i) {
    int e = tid + i * 256; int rr = e >> 5, cc = e & 31;
    O[(size_t)(n0 + rr) * 1024 + k0 + cc] = (bf16)tile[cc][rr];
  }
}

// ------- GEMM v4: 128x256 tile, BK=64, 8 waves (2M x 4N, 64x64 each),
// TRIPLE-buffered LDS (3 x 48KB dynamic) with prefetch distance = 2 K-tiles.
// One s_waitcnt vmcnt(6)+s_barrier per K-tile; never drains to 0 in the
// main loop. 2 phases/tile, setprio(1) around each 16-MFMA cluster.
// XOR-swizzled staging on the GLOBAL source; linear LDS dest.
// (unchanged; 4 clean verified runs)
template <int MODE>
__global__ __launch_bounds__(512, 2) void gemm_kernel(
    const bf16* __restrict__ A,
    const bf16* __restrict__ Bt0, const bf16* __restrict__ Bt1,
    const bf16* __restrict__ Bt2,
    bf16* __restrict__ Qo, bf16* __restrict__ Ko, bf16* __restrict__ Vto,
    const float* __restrict__ xres, float* __restrict__ out) {
  extern __shared__ float4 smem4[];
  bf16* smem = (bf16*)smem4;  // 3 buffers x 24576 elems (A 8192 + B 16384)

  constexpr int NWG = (MODE == 0) ? 768 : 256;
  constexpr int CPX = NWG / 8;
  constexpr int NBN = (MODE == 0) ? 12 : 4;
  const int wg = ((int)blockIdx.x & 7) * CPX + ((int)blockIdx.x >> 3);
  const int bn = wg % NBN, bm = wg / NBN;

  const bf16* Bt;
  int n0full = 0, wsel = 0;
  if constexpr (MODE == 0) {
    wsel = bn >> 2;
    Bt = (wsel == 0) ? Bt0 : (wsel == 1 ? Bt1 : Bt2);
    n0full = (bn & 3) * 256;
  } else {
    Bt = Bt0;
    n0full = bn * 256;
  }

  const int tid = threadIdx.x;
  const int wave = tid >> 6, lane = tid & 63;
  const int quad = lane >> 4, r = lane & 15;
  const int wm = (wave >> 2) * 64, wn = (wave & 3) * 64;

  // ---- staging setup: 6 x 1KB-slab loads per thread per K-tile ----
  const int lrow = lane >> 3;
  const int lcol = ((lane & 7) ^ lrow) * 8;  // pre-swizzled global chunk
  const int am0 = bm * 128 + wave * 8 + lrow;
  const int am1 = am0 + 64;
  const bf16 *p0, *p1, *p2, *p3, *p4, *p5;
  if constexpr (MODE == 0) {
    p0 = A + (size_t)am0 * 1024 + lcol;
    p1 = A + (size_t)am1 * 1024 + lcol;
  } else {
    p0 = A + (size_t)(am0 >> 11) * (16 * (size_t)S_ * DH_) +
         (size_t)(am0 & 2047) * 64 + lcol;
    p1 = A + (size_t)(am1 >> 11) * (16 * (size_t)S_ * DH_) +
         (size_t)(am1 & 2047) * 64 + lcol;
  }
  const int bnr = n0full + wave * 8 + lrow;
  p2 = Bt + (size_t)bnr * 1024 + lcol;
  p3 = Bt + (size_t)(bnr + 64) * 1024 + lcol;
  p4 = Bt + (size_t)(bnr + 128) * 1024 + lcol;
  p5 = Bt + (size_t)(bnr + 192) * 1024 + lcol;
  constexpr ptrdiff_t dA = (MODE == 0) ? 64 : (ptrdiff_t)S_ * DH_;

  const int oA0 = wave * 512, oA1 = (8 + wave) * 512;
  const int oB0 = 8192 + wave * 512, oB1 = 8192 + (8 + wave) * 512;
  const int oB2 = 8192 + (16 + wave) * 512, oB3 = 8192 + (24 + wave) * 512;

  auto stage = [&](bf16* base) {
    g2lds16(p0, base + oA0); p0 += dA;
    g2lds16(p1, base + oA1); p1 += dA;
    g2lds16(p2, base + oB0); p2 += 64;
    g2lds16(p3, base + oB1); p3 += 64;
    g2lds16(p4, base + oB2); p4 += 64;
    g2lds16(p5, base + oB3); p5 += 64;
  };

  f32x4 acc[4][4];
  const f32x4 zero = {0.f, 0.f, 0.f, 0.f};
#pragma unroll
  for (int i = 0; i < 4; ++i)
#pragma unroll
    for (int j = 0; j < 4; ++j) acc[i][j] = zero;

  const int rw = r & 7;
  const int x0 = (quad ^ rw) * 8;        // k-step 0 chunk position
  const int x1 = ((quad + 4) ^ rw) * 8;  // k-step 1
  const int raB = (wm + r) * 64;
  const int rbB = (wn + r) * 64;

  auto phases = [&](const bf16* buf) {
    const bf16* bA = buf;
    const bf16* bB = buf + 8192;
    bf16x8 af[4], bg[4];
    // ---- phase 1: k 0..31
#pragma unroll
    for (int i = 0; i < 4; ++i)
      af[i] = *(const bf16x8*)(bA + raB + i * 1024 + x0);
#pragma unroll
    for (int j = 0; j < 4; ++j)
      bg[j] = *(const bf16x8*)(bB + rbB + j * 1024 + x0);
    __builtin_amdgcn_s_setprio(1);
#pragma unroll
    for (int i = 0; i < 4; ++i)
#pragma unroll
      for (int j = 0; j < 4; ++j)
        acc[i][j] = __builtin_amdgcn_mfma_f32_16x16x32_bf16(af[i], bg[j],
                                                            acc[i][j], 0, 0, 0);
    __builtin_amdgcn_s_setprio(0);
    asm volatile("s_barrier" ::: "memory");
    // ---- phase 2: k 32..63
#pragma unroll
    for (int i = 0; i < 4; ++i)
      af[i] = *(const bf16x8*)(bA + raB + i * 1024 + x1);
#pragma unroll
    for (int j = 0; j < 4; ++j)
      bg[j] = *(const bf16x8*)(bB + rbB + j * 1024 + x1);
    __builtin_amdgcn_s_setprio(1);
#pragma unroll
    for (int i = 0; i < 4; ++i)
#pragma unroll
      for (int j = 0; j < 4; ++j)
        acc[i][j] = __builtin_amdgcn_mfma_f32_16x16x32_bf16(af[i], bg[j],
                                                            acc[i][j], 0, 0, 0);
    __builtin_amdgcn_s_setprio(0);
  };

  bf16* b0 = smem;
  bf16* b1 = smem + 24576;
  bf16* b2 = smem + 49152;

  stage(b0);
  stage(b1);

#pragma unroll 1
  for (int kt = 0; kt < 15; kt += 3) {
    asm volatile("s_waitcnt vmcnt(6)\n\ts_barrier" ::: "memory");
    stage(b2);                    // tile kt+2
    phases(b0);                   // tile kt
    asm volatile("s_waitcnt vmcnt(6)\n\ts_barrier" ::: "memory");
    stage(b0);                    // tile kt+3
    phases(b1);                   // tile kt+1
    asm volatile("s_waitcnt vmcnt(6)\n\ts_barrier" ::: "memory");
    if (kt < 12) stage(b1);       // tile kt+4 (skip nonexistent tile 16)
    phases(b2);                   // tile kt+2
  }
  asm volatile("s_waitcnt vmcnt(0)\n\ts_barrier" ::: "memory");
  phases(b0);                     // tile 15

  // ---- epilogue ----
  const int mB = bm * 128 + wm + quad * 4;
  if constexpr (MODE == 0) {
    if (wsel < 2) {
      bf16* dst = (wsel == 0) ? Qo : Ko;
#pragma unroll
      for (int i = 0; i < 4; ++i) {
#pragma unroll
        for (int j = 0; j < 4; ++j) {
          int n = n0full + wn + j * 16 + r;
          int h = n >> 6, dh = n & 63;
#pragma unroll
          for (int g = 0; g < 4; ++g) {
            int m = mB + i * 16 + g;
            int b = m >> 11, s = m & 2047;
            dst[((size_t)(b * H_ + h) * S_ + s) * DH_ + dh] =
                (bf16)acc[i][j][g];
          }
        }
      }
    } else {  // V: store transposed [B,H,DH,S]
#pragma unroll
      for (int i = 0; i < 4; ++i) {
        int m = mB + i * 16;
        int b = m >> 11, s = m & 2047;
#pragma unroll
        for (int j = 0; j < 4; ++j) {
          int n = n0full + wn + j * 16 + r;
          int h = n >> 6, dh = n & 63;
          bf16x4 pk;
#pragma unroll
          for (int g = 0; g < 4; ++g) pk[g] = (bf16)acc[i][j][g];
          *(bf16x4*)(Vto + ((size_t)(b * H_ + h) * DH_ + dh) * S_ + s) = pk;
        }
      }
    }
  } else {
#pragma unroll
    for (int i = 0; i < 4; ++i) {
#pragma unroll
      for (int j = 0; j < 4; ++j) {
        int n = bn * 256 + wn + j * 16 + r;
#pragma unroll
        for (int g = 0; g < 4; ++g) {
          int m = mB + i * 16 + g;
          size_t idx = (size_t)m * 1024 + n;
          out[idx] = acc[i][j][g] + xres[idx];
        }
      }
    }
  }
}

// ------ flash attention v9: one 256-q tile per block, 2 blocks/CU ------
// Round-4 post-mortem: attn is latency/serial-chain bound, not LDS-bound.
// v8's full-drain-per-tile stalls all waves of the ONLY resident block
// during each prefetch drain. Fix: grid 512 (all co-resident, 2 blocks/CU,
// 16 waves/CU) so the other block's compute covers the drain. Inner loop
// and sync are byte-identical to v8 (race-hardened full drain per tile).
// Load balance across dispatch rounds: blocks 0..255 take heavy tiles
// i=7-(bx>>6) in {7..4}; blocks 256..511 take complementary i=(bx-256)>>6
// in {0..3} -> every CU hosts heavy+light = 36 iters total.
__global__ __launch_bounds__(512, 4) void attn_kernel(const bf16* __restrict__ Qb,
                                                      const bf16* __restrict__ Kb,
                                                      const bf16* __restrict__ Vtb,
                                                      bf16* __restrict__ ctx) {
  __shared__ __align__(16) bf16 smK[2][64 * 64];
  __shared__ __align__(16) bf16 smV[2][64 * 64];
  const int bx = blockIdx.x;
  const int bh = bx & 63;
  const int i256 = (bx < 256) ? (7 - (bx >> 6)) : ((bx - 256) >> 6);
  const bf16* Qh = Qb + (size_t)bh * S_ * DH_;
  const bf16* Kh = Kb + (size_t)bh * S_ * DH_;
  const bf16* Vh = Vtb + (size_t)bh * DH_ * S_;
  bf16* Ch = ctx + (size_t)bh * S_ * DH_;
  const int tid = threadIdx.x, wave = tid >> 6, lane = tid & 63;
  const int quad = lane >> 4, r = lane & 15;
  const int r7 = r & 7;
  const int wrow = wave * 8 + (lane >> 3);         // staging row (of 64)
  const int gcol = ((lane & 7) ^ (lane >> 3)) * 8; // source-side XOR swizzle
  const f32x4 zero = {0.f, 0.f, 0.f, 0.f};
  const int xk0 = (quad ^ r7) * 8, xk1 = ((quad + 4) ^ r7) * 8;

  const int q0w = i256 * 256 + wave * 32;
  const int numkt = 4 * i256 + 4;
  const int lastkt = q0w >> 6;  // per-wave: last active tile == mask tile

  bf16x8 qf[2][2];
  const float qsc = 0.125f * 1.44269504f;  // 1/sqrt(64) * log2(e)
#pragma unroll
  for (int qg = 0; qg < 2; ++qg)
#pragma unroll
    for (int hh = 0; hh < 2; ++hh) {
      bf16x8 q = *(const bf16x8*)(Qh + (size_t)(q0w + qg * 16 + r) * DH_ +
                                  hh * 32 + quad * 8);
#pragma unroll
      for (int i = 0; i < 8; ++i) q[i] = (bf16)((float)q[i] * qsc);
      qf[qg][hh] = q;
    }

  f32x4 lacc[2] = {zero, zero};
  f32x4 oacc[2][4];
#pragma unroll
  for (int qg = 0; qg < 2; ++qg)
#pragma unroll
    for (int tn = 0; tn < 4; ++tn) oacc[qg][tn] = zero;

  // prologue: tile 0 -> buffer 0, full drain
  g2lds16(Kh + (size_t)wrow * DH_ + gcol, &smK[0][wave * 512]);
  g2lds16(Vh + (size_t)wrow * S_ + gcol, &smV[0][wave * 512]);
  asm volatile("s_waitcnt vmcnt(0)\n\ts_barrier" ::: "memory");

  for (int kt = 0; kt < numkt; ++kt) {
    const int cur = kt & 1;
    const int kv0 = kt * 64;
    if (kt + 1 < numkt) {  // issue next-tile loads early (overlap compute)
      const int nk = kv0 + 64;
      g2lds16(Kh + (size_t)(nk + wrow) * DH_ + gcol, &smK[1 - cur][wave * 512]);
      g2lds16(Vh + (size_t)wrow * S_ + nk + gcol, &smV[1 - cur][wave * 512]);
    }
    if (kt <= lastkt) {  // wave not fully masked for this kv tile
      const bf16* kb = &smK[cur][0];
      const bf16* vb = &smV[cur][0];

      // S^T: s[qg][t][g] = S[kv=kv0+t*16+quad*4+g][q=q0w+qg*16+r]
      f32x4 s[2][4];
#pragma unroll
      for (int t = 0; t < 4; ++t) {
        bf16x8 kf0 = *(const bf16x8*)(kb + (t * 16 + r) * 64 + xk0);
        bf16x8 kf1 = *(const bf16x8*)(kb + (t * 16 + r) * 64 + xk1);
#pragma unroll
        for (int qg = 0; qg < 2; ++qg) {
          f32x4 z = __builtin_amdgcn_mfma_f32_16x16x32_bf16(kf0, qf[qg][0],
                                                            zero, 0, 0, 0);
          s[qg][t] = __builtin_amdgcn_mfma_f32_16x16x32_bf16(kf1, qf[qg][1],
                                                             z, 0, 0, 0);
        }
      }
      if (kt == lastkt) {  // exactly one diagonal tile per wave
#pragma unroll
        for (int qg = 0; qg < 2; ++qg) {
          const int q = q0w + qg * 16 + r;
#pragma unroll
          for (int t = 0; t < 4; ++t) {
            const int kv = kv0 + t * 16 + quad * 4;
#pragma unroll
            for (int g = 0; g < 4; ++g)
              if (kv + g > q) s[qg][t][g] = -1e30f;
          }
        }
      }
      // P = exp2(s); l accumulate; PV via 16x16x16 MFMA (P from registers)
#pragma unroll
      for (int t = 0; t < 4; ++t) {
        bf16x4 pa[2];
#pragma unroll
        for (int qg = 0; qg < 2; ++qg) {
#pragma unroll
          for (int g = 0; g < 4; ++g)
            s[qg][t][g] = __builtin_amdgcn_exp2f(s[qg][t][g]);
          lacc[qg] += s[qg][t];
          bf16x4 pk;
#pragma unroll
          for (int g = 0; g < 4; ++g) pk[g] = (bf16)s[qg][t][g];
          pa[qg] = pk;
        }
#pragma unroll
        for (int tn = 0; tn < 4; ++tn) {
          bf16x4 vf = *(const bf16x4*)(
              vb + (tn * 16 + r) * 64 +
              ((2 * t + (quad >> 1)) ^ r7) * 8 + (quad & 1) * 4);
          oacc[0][tn] = mfma16(pa[0], vf, oacc[0][tn]);
          oacc[1][tn] = mfma16(pa[1], vf, oacc[1][tn]);
        }
      }
    }
    // ONE full drain per tile: next tile landed in LDS, all LDS reads
    // retired, all waves synced. Nothing outstanding crosses this point.
    asm volatile("s_waitcnt vmcnt(0) lgkmcnt(0)\n\ts_barrier" ::: "memory");
  }

  // epilogue: reduce l per q (= lane r) per qg, normalize, store
#pragma unroll
  for (int qg = 0; qg < 2; ++qg) {
    float rs = (lacc[qg][0] + lacc[qg][1]) + (lacc[qg][2] + lacc[qg][3]);
    rs += __shfl_xor(rs, 16, 64);
    rs += __shfl_xor(rs, 32, 64);
    const float inv = 1.f / rs;
    f32x4 ib;
#pragma unroll
    for (int g = 0; g < 4; ++g) ib[g] = __shfl(inv, quad * 4 + g, 64);
#pragma unroll
    for (int tn = 0; tn < 4; ++tn) {
      f32x4 ov = oacc[qg][tn] * ib;
#pragma unroll
      for (int g = 0; g < 4; ++g)
        Ch[(size_t)(q0w + qg * 16 + quad * 4 + g) * DH_ + tn * 16 + r] =
            (bf16)ov[g];
    }
  }
}

// ---------------- LayerNorm in-place on d_out ----------------
__global__ __launch_bounds__(256) void ln_kernel(float* __restrict__ out,
                                                 const float* __restrict__ gamma,
                                                 const float* __restrict__ beta) {
  __shared__ float red[8];
  size_t row = blockIdx.x;
  float* p = out + row * 1024;
  int tid = threadIdx.x;
  float4 v = ((const float4*)p)[tid];
  float s1 = v.x + v.y + v.z + v.w;
  float s2 = v.x * v.x + v.y * v.y + v.z * v.z + v.w * v.w;
#pragma unroll
  for (int o = 1; o < 64; o <<= 1) {
    s1 += __shfl_xor(s1, o, 64);
    s2 += __shfl_xor(s2, o, 64);
  }
  int wave = tid >> 6, lane = tid & 63;
  if (lane == 0) { red[wave] = s1; red[4 + wave] = s2; }
  __syncthreads();
  s1 = red[0] + red[1] + red[2] + red[3];
  s2 = red[4] + red[5] + red[6] + red[7];
  float mean = s1 * (1.f / 1024.f);
  float var = s2 * (1.f / 1024.f) - mean * mean;
  float rstd = rsqrtf(var + 1e-5f);
  float4 g = ((const float4*)gamma)[tid];
  float4 b = ((const float4*)beta)[tid];
  float4 o;
  o.x = (v.x - mean) * rstd * g.x + b.x;
  o.y = (v.y - mean) * rstd * g.y + b.y;
  o.z = (v.z - mean) * rstd * g.z + b.z;
  o.w = (v.w - mean) * rstd * g.w + b.w;
  ((float4*)p)[tid] = o;
}

extern "C" void kernel_launch(void* const* d_in, const int* in_sizes, int n_in,
                              void* d_out, int out_size, void* d_ws,
                              size_t ws_size, hipStream_t stream) {
  (void)in_sizes; (void)n_in; (void)out_size; (void)ws_size;
  const float* x  = (const float*)d_in[0];
  const float* WQ = (const float*)d_in[1];
  const float* WK = (const float*)d_in[2];
  const float* WV = (const float*)d_in[3];
  const float* WO = (const float*)d_in[4];
  const float* gamma = (const float*)d_in[5];
  const float* beta  = (const float*)d_in[6];
  float* out = (float*)d_out;

  bf16* ws = (bf16*)d_ws;
  const size_t MD = (size_t)M_ * D_;
  const size_t WW = (size_t)D_ * D_;
  bf16* xb   = ws;
  bf16* wqt  = xb + MD;
  bf16* wkt  = wqt + WW;
  bf16* wvt  = wkt + WW;
  bf16* wot  = wvt + WW;
  bf16* Qb   = wot + WW;
  bf16* Kb   = Qb + MD;
  bf16* Vtb  = Kb + MD;
  bf16* ctxb = Vtb + MD;

  constexpr int GEMM_LDS = 3 * 48 * 1024;  // 147456 B
  static bool s_attr = false;
  if (!s_attr) {
    s_attr = true;
    (void)hipFuncSetAttribute(reinterpret_cast<const void*>(gemm_kernel<0>),
                              hipFuncAttributeMaxDynamicSharedMemorySize,
                              GEMM_LDS);
    (void)hipFuncSetAttribute(reinterpret_cast<const void*>(gemm_kernel<1>),
                              hipFuncAttributeMaxDynamicSharedMemorySize,
                              GEMM_LDS);
  }

  cvt_all_kernel<<<dim3(8192), dim3(256), 0, stream>>>(
      x, WQ, WK, WV, WO, xb, wqt, wkt, wvt, wot);
  gemm_kernel<0><<<dim3(768), dim3(512), GEMM_LDS, stream>>>(
      xb, wqt, wkt, wvt, Qb, Kb, Vtb, nullptr, nullptr);
  attn_kernel<<<dim3(512), dim3(512), 0, stream>>>(Qb, Kb, Vtb, ctxb);
  gemm_kernel<1><<<dim3(256), dim3(512), GEMM_LDS, stream>>>(
      ctxb, wot, nullptr, nullptr, nullptr, nullptr, nullptr, x, out);
  ln_kernel<<<dim3(8192), dim3(256), 0, stream>>>(out, gamma, beta);
}

// Round 6
// 261.160 us; speedup vs baseline: 1.0049x; 1.0049x over previous
//
#include <hip/hip_runtime.h>
#include <hip/hip_bf16.h>
#include <cstdint>
#include <cstddef>

// B=4, S=2048, D=1024, H=16, DH=64, M = B*S = 8192
#define S_ 2048
#define D_ 1024
#define H_ 16
#define DH_ 64
#define M_ 8192

using bf16 = __bf16;
using bf16x4 = __attribute__((ext_vector_type(4))) __bf16;
using bf16x8 = __attribute__((ext_vector_type(8))) __bf16;
using f32x4 = __attribute__((ext_vector_type(4))) float;
using s16x4 = __attribute__((ext_vector_type(4))) short;

__device__ __forceinline__ void g2lds16(const bf16* g, bf16* l) {
  __builtin_amdgcn_global_load_lds(
      (const __attribute__((address_space(1))) void*)g,
      (__attribute__((address_space(3))) void*)l, 16, 0, 0);
}

// 16x16x16 bf16 MFMA (used by attn PV)
__device__ __forceinline__ f32x4 mfma16(bf16x4 a, bf16x4 b, f32x4 c) {
#if __has_builtin(__builtin_amdgcn_mfma_f32_16x16x16_bf16)
  return __builtin_amdgcn_mfma_f32_16x16x16_bf16(a, b, c, 0, 0, 0);
#elif __has_builtin(__builtin_amdgcn_mfma_f32_16x16x16bf16_1k)
  return __builtin_amdgcn_mfma_f32_16x16x16bf16_1k(
      __builtin_bit_cast(s16x4, a), __builtin_bit_cast(s16x4, b), c, 0, 0, 0);
#else
  f32x4 d;
  asm("v_mfma_f32_16x16x16_bf16 %0, %1, %2, %3"
      : "=v"(d)
      : "v"(a), "v"(b), "v"(c));
  return d;
#endif
}

// ------- fused fp32->bf16 converts: x (blocks 0..4095) + 4 weights^T -------
__global__ __launch_bounds__(256) void cvt_all_kernel(
    const float* __restrict__ x, const float* __restrict__ w0,
    const float* __restrict__ w1, const float* __restrict__ w2,
    const float* __restrict__ w3, bf16* __restrict__ xb,
    bf16* __restrict__ o0, bf16* __restrict__ o1, bf16* __restrict__ o2,
    bf16* __restrict__ o3) {
  __shared__ float tile[32][33];
  int bx = blockIdx.x;
  int tid = threadIdx.x;
  if (bx < 4096) {
    size_t i = ((size_t)bx * 256 + tid) * 8;
    float4 a = *(const float4*)(x + i);
    float4 b = *(const float4*)(x + i + 4);
    bf16x8 o;
    o[0] = (bf16)a.x; o[1] = (bf16)a.y; o[2] = (bf16)a.z; o[3] = (bf16)a.w;
    o[4] = (bf16)b.x; o[5] = (bf16)b.y; o[6] = (bf16)b.z; o[7] = (bf16)b.w;
    *(bf16x8*)(xb + i) = o;
    return;
  }
  int wb = bx - 4096;
  int wsel = wb >> 10; wb &= 1023;
  const float* W; bf16* O;
  switch (wsel) {
    case 0: W = w0; O = o0; break;
    case 1: W = w1; O = o1; break;
    case 2: W = w2; O = o2; break;
    default: W = w3; O = o3; break;
  }
  int n0 = (wb & 31) * 32;
  int k0 = (wb >> 5) * 32;
#pragma unroll
  for (int i = 0; i < 4; ++i) {
    int e = tid + i * 256; int rr = e >> 5, cc = e & 31;
    tile[rr][cc] = W[(size_t)(k0 + rr) * 1024 + n0 + cc];
  }
  __syncthreads();
#pragma unroll
  for (int i = 0; i < 4; ++i) {
    int e = tid + i * 256; int rr = e >> 5, cc = e & 31;
    O[(size_t)(n0 + rr) * 1024 + k0 + cc] = (bf16)tile[cc][rr];
  }
}

// ------- GEMM v5: 128x256 tile, BK=64, 8 waves (2M x 4N, 64x64 each),
// TRIPLE-buffered LDS, prefetch distance 2 K-tiles, vmcnt(6) counted wait
// at tile boundaries only. Round-6 change: REMOVED the mid-tile s_barrier
// between the two k-phases — it had no correctness role (both phases read
// the same already-synced buffer; overwrite safety comes from the
// tile-boundary vmcnt+barrier). This de-lockstemps the 8 waves so ds_read,
// MFMA and staging from different waves overlap on the CU pipes.
template <int MODE>
__global__ __launch_bounds__(512, 2) void gemm_kernel(
    const bf16* __restrict__ A,
    const bf16* __restrict__ Bt0, const bf16* __restrict__ Bt1,
    const bf16* __restrict__ Bt2,
    bf16* __restrict__ Qo, bf16* __restrict__ Ko, bf16* __restrict__ Vto,
    const float* __restrict__ xres, float* __restrict__ out) {
  extern __shared__ float4 smem4[];
  bf16* smem = (bf16*)smem4;  // 3 buffers x 24576 elems (A 8192 + B 16384)

  constexpr int NWG = (MODE == 0) ? 768 : 256;
  constexpr int CPX = NWG / 8;
  constexpr int NBN = (MODE == 0) ? 12 : 4;
  const int wg = ((int)blockIdx.x & 7) * CPX + ((int)blockIdx.x >> 3);
  const int bn = wg % NBN, bm = wg / NBN;

  const bf16* Bt;
  int n0full = 0, wsel = 0;
  if constexpr (MODE == 0) {
    wsel = bn >> 2;
    Bt = (wsel == 0) ? Bt0 : (wsel == 1 ? Bt1 : Bt2);
    n0full = (bn & 3) * 256;
  } else {
    Bt = Bt0;
    n0full = bn * 256;
  }

  const int tid = threadIdx.x;
  const int wave = tid >> 6, lane = tid & 63;
  const int quad = lane >> 4, r = lane & 15;
  const int wm = (wave >> 2) * 64, wn = (wave & 3) * 64;

  // ---- staging setup: 6 x 1KB-slab loads per thread per K-tile ----
  const int lrow = lane >> 3;
  const int lcol = ((lane & 7) ^ lrow) * 8;  // pre-swizzled global chunk
  const int am0 = bm * 128 + wave * 8 + lrow;
  const int am1 = am0 + 64;
  const bf16 *p0, *p1, *p2, *p3, *p4, *p5;
  if constexpr (MODE == 0) {
    p0 = A + (size_t)am0 * 1024 + lcol;
    p1 = A + (size_t)am1 * 1024 + lcol;
  } else {
    p0 = A + (size_t)(am0 >> 11) * (16 * (size_t)S_ * DH_) +
         (size_t)(am0 & 2047) * 64 + lcol;
    p1 = A + (size_t)(am1 >> 11) * (16 * (size_t)S_ * DH_) +
         (size_t)(am1 & 2047) * 64 + lcol;
  }
  const int bnr = n0full + wave * 8 + lrow;
  p2 = Bt + (size_t)bnr * 1024 + lcol;
  p3 = Bt + (size_t)(bnr + 64) * 1024 + lcol;
  p4 = Bt + (size_t)(bnr + 128) * 1024 + lcol;
  p5 = Bt + (size_t)(bnr + 192) * 1024 + lcol;
  constexpr ptrdiff_t dA = (MODE == 0) ? 64 : (ptrdiff_t)S_ * DH_;

  const int oA0 = wave * 512, oA1 = (8 + wave) * 512;
  const int oB0 = 8192 + wave * 512, oB1 = 8192 + (8 + wave) * 512;
  const int oB2 = 8192 + (16 + wave) * 512, oB3 = 8192 + (24 + wave) * 512;

  auto stage = [&](bf16* base) {
    g2lds16(p0, base + oA0); p0 += dA;
    g2lds16(p1, base + oA1); p1 += dA;
    g2lds16(p2, base + oB0); p2 += 64;
    g2lds16(p3, base + oB1); p3 += 64;
    g2lds16(p4, base + oB2); p4 += 64;
    g2lds16(p5, base + oB3); p5 += 64;
  };

  f32x4 acc[4][4];
  const f32x4 zero = {0.f, 0.f, 0.f, 0.f};
#pragma unroll
  for (int i = 0; i < 4; ++i)
#pragma unroll
    for (int j = 0; j < 4; ++j) acc[i][j] = zero;

  const int rw = r & 7;
  const int x0 = (quad ^ rw) * 8;        // k-step 0 chunk position
  const int x1 = ((quad + 4) ^ rw) * 8;  // k-step 1
  const int raB = (wm + r) * 64;
  const int rbB = (wn + r) * 64;

  auto phases = [&](const bf16* buf) {
    const bf16* bA = buf;
    const bf16* bB = buf + 8192;
    bf16x8 af[4], bg[4];
    // ---- phase 1: k 0..31
#pragma unroll
    for (int i = 0; i < 4; ++i)
      af[i] = *(const bf16x8*)(bA + raB + i * 1024 + x0);
#pragma unroll
    for (int j = 0; j < 4; ++j)
      bg[j] = *(const bf16x8*)(bB + rbB + j * 1024 + x0);
    __builtin_amdgcn_s_setprio(1);
#pragma unroll
    for (int i = 0; i < 4; ++i)
#pragma unroll
      for (int j = 0; j < 4; ++j)
        acc[i][j] = __builtin_amdgcn_mfma_f32_16x16x32_bf16(af[i], bg[j],
                                                            acc[i][j], 0, 0, 0);
    __builtin_amdgcn_s_setprio(0);
    // (mid-tile barrier removed: same buffer, no hazard — scheduling only)
    // ---- phase 2: k 32..63
#pragma unroll
    for (int i = 0; i < 4; ++i)
      af[i] = *(const bf16x8*)(bA + raB + i * 1024 + x1);
#pragma unroll
    for (int j = 0; j < 4; ++j)
      bg[j] = *(const bf16x8*)(bB + rbB + j * 1024 + x1);
    __builtin_amdgcn_s_setprio(1);
#pragma unroll
    for (int i = 0; i < 4; ++i)
#pragma unroll
      for (int j = 0; j < 4; ++j)
        acc[i][j] = __builtin_amdgcn_mfma_f32_16x16x32_bf16(af[i], bg[j],
                                                            acc[i][j], 0, 0, 0);
    __builtin_amdgcn_s_setprio(0);
  };

  bf16* b0 = smem;
  bf16* b1 = smem + 24576;
  bf16* b2 = smem + 49152;

  stage(b0);
  stage(b1);

#pragma unroll 1
  for (int kt = 0; kt < 15; kt += 3) {
    asm volatile("s_waitcnt vmcnt(6)\n\ts_barrier" ::: "memory");
    stage(b2);                    // tile kt+2
    phases(b0);                   // tile kt
    asm volatile("s_waitcnt vmcnt(6)\n\ts_barrier" ::: "memory");
    stage(b0);                    // tile kt+3
    phases(b1);                   // tile kt+1
    asm volatile("s_waitcnt vmcnt(6)\n\ts_barrier" ::: "memory");
    if (kt < 12) stage(b1);       // tile kt+4 (skip nonexistent tile 16)
    phases(b2);                   // tile kt+2
  }
  asm volatile("s_waitcnt vmcnt(0)\n\ts_barrier" ::: "memory");
  phases(b0);                     // tile 15

  // ---- epilogue ----
  const int mB = bm * 128 + wm + quad * 4;
  if constexpr (MODE == 0) {
    if (wsel < 2) {
      bf16* dst = (wsel == 0) ? Qo : Ko;
#pragma unroll
      for (int i = 0; i < 4; ++i) {
#pragma unroll
        for (int j = 0; j < 4; ++j) {
          int n = n0full + wn + j * 16 + r;
          int h = n >> 6, dh = n & 63;
#pragma unroll
          for (int g = 0; g < 4; ++g) {
            int m = mB + i * 16 + g;
            int b = m >> 11, s = m & 2047;
            dst[((size_t)(b * H_ + h) * S_ + s) * DH_ + dh] =
                (bf16)acc[i][j][g];
          }
        }
      }
    } else {  // V: store transposed [B,H,DH,S]
#pragma unroll
      for (int i = 0; i < 4; ++i) {
        int m = mB + i * 16;
        int b = m >> 11, s = m & 2047;
#pragma unroll
        for (int j = 0; j < 4; ++j) {
          int n = n0full + wn + j * 16 + r;
          int h = n >> 6, dh = n & 63;
          bf16x4 pk;
#pragma unroll
          for (int g = 0; g < 4; ++g) pk[g] = (bf16)acc[i][j][g];
          *(bf16x4*)(Vto + ((size_t)(b * H_ + h) * DH_ + dh) * S_ + s) = pk;
        }
      }
    }
  } else {
#pragma unroll
    for (int i = 0; i < 4; ++i) {
#pragma unroll
      for (int j = 0; j < 4; ++j) {
        int n = bn * 256 + wn + j * 16 + r;
#pragma unroll
        for (int g = 0; g < 4; ++g) {
          int m = mB + i * 16 + g;
          size_t idx = (size_t)m * 1024 + n;
          out[idx] = acc[i][j][g] + xres[idx];
        }
      }
    }
  }
}

// ------ flash attention v10: v9 geometry/sync + pipe de-lockstepping ------
// Round-5 post-mortem: MFMA+VALU+LDS each ~1/3 busy, wall ~= their SUM ->
// lockstep waves want the same pipe simultaneously. Round-6: (a) T5
// setprio(1) around QK and PV MFMA clusters; (b) split per-tile softmax
// into a pure-VALU block (all exp2/cvt/lacc -> pa[2][4]) then a pure-MFMA
// block (V reads + 32 PV MFMA). Pure clusters + setprio let drifting waves
// overlap VALU vs MFMA vs LDS. Sync drain points byte-identical to v9.
__global__ __launch_bounds__(512, 4) void attn_kernel(const bf16* __restrict__ Qb,
                                                      const bf16* __restrict__ Kb,
                                                      const bf16* __restrict__ Vtb,
                                                      bf16* __restrict__ ctx) {
  __shared__ __align__(16) bf16 smK[2][64 * 64];
  __shared__ __align__(16) bf16 smV[2][64 * 64];
  const int bx = blockIdx.x;
  const int bh = bx & 63;
  const int i256 = (bx < 256) ? (7 - (bx >> 6)) : ((bx - 256) >> 6);
  const bf16* Qh = Qb + (size_t)bh * S_ * DH_;
  const bf16* Kh = Kb + (size_t)bh * S_ * DH_;
  const bf16* Vh = Vtb + (size_t)bh * DH_ * S_;
  bf16* Ch = ctx + (size_t)bh * S_ * DH_;
  const int tid = threadIdx.x, wave = tid >> 6, lane = tid & 63;
  const int quad = lane >> 4, r = lane & 15;
  const int r7 = r & 7;
  const int wrow = wave * 8 + (lane >> 3);         // staging row (of 64)
  const int gcol = ((lane & 7) ^ (lane >> 3)) * 8; // source-side XOR swizzle
  const f32x4 zero = {0.f, 0.f, 0.f, 0.f};
  const int xk0 = (quad ^ r7) * 8, xk1 = ((quad + 4) ^ r7) * 8;

  const int q0w = i256 * 256 + wave * 32;
  const int numkt = 4 * i256 + 4;
  const int lastkt = q0w >> 6;  // per-wave: last active tile == mask tile

  bf16x8 qf[2][2];
  const float qsc = 0.125f * 1.44269504f;  // 1/sqrt(64) * log2(e)
#pragma unroll
  for (int qg = 0; qg < 2; ++qg)
#pragma unroll
    for (int hh = 0; hh < 2; ++hh) {
      bf16x8 q = *(const bf16x8*)(Qh + (size_t)(q0w + qg * 16 + r) * DH_ +
                                  hh * 32 + quad * 8);
#pragma unroll
      for (int i = 0; i < 8; ++i) q[i] = (bf16)((float)q[i] * qsc);
      qf[qg][hh] = q;
    }

  f32x4 lacc[2] = {zero, zero};
  f32x4 oacc[2][4];
#pragma unroll
  for (int qg = 0; qg < 2; ++qg)
#pragma unroll
    for (int tn = 0; tn < 4; ++tn) oacc[qg][tn] = zero;

  // prologue: tile 0 -> buffer 0, full drain
  g2lds16(Kh + (size_t)wrow * DH_ + gcol, &smK[0][wave * 512]);
  g2lds16(Vh + (size_t)wrow * S_ + gcol, &smV[0][wave * 512]);
  asm volatile("s_waitcnt vmcnt(0)\n\ts_barrier" ::: "memory");

  for (int kt = 0; kt < numkt; ++kt) {
    const int cur = kt & 1;
    const int kv0 = kt * 64;
    if (kt + 1 < numkt) {  // issue next-tile loads early (overlap compute)
      const int nk = kv0 + 64;
      g2lds16(Kh + (size_t)(nk + wrow) * DH_ + gcol, &smK[1 - cur][wave * 512]);
      g2lds16(Vh + (size_t)wrow * S_ + nk + gcol, &smV[1 - cur][wave * 512]);
    }
    if (kt <= lastkt) {  // wave not fully masked for this kv tile
      const bf16* kb = &smK[cur][0];
      const bf16* vb = &smV[cur][0];

      // ---- QK^T MFMA cluster (setprio) ----
      // S^T: s[qg][t][g] = S[kv=kv0+t*16+quad*4+g][q=q0w+qg*16+r]
      f32x4 s[2][4];
      __builtin_amdgcn_s_setprio(1);
#pragma unroll
      for (int t = 0; t < 4; ++t) {
        bf16x8 kf0 = *(const bf16x8*)(kb + (t * 16 + r) * 64 + xk0);
        bf16x8 kf1 = *(const bf16x8*)(kb + (t * 16 + r) * 64 + xk1);
#pragma unroll
        for (int qg = 0; qg < 2; ++qg) {
          f32x4 z = __builtin_amdgcn_mfma_f32_16x16x32_bf16(kf0, qf[qg][0],
                                                            zero, 0, 0, 0);
          s[qg][t] = __builtin_amdgcn_mfma_f32_16x16x32_bf16(kf1, qf[qg][1],
                                                             z, 0, 0, 0);
        }
      }
      __builtin_amdgcn_s_setprio(0);
      if (kt == lastkt) {  // exactly one diagonal tile per wave
#pragma unroll
        for (int qg = 0; qg < 2; ++qg) {
          const int q = q0w + qg * 16 + r;
#pragma unroll
          for (int t = 0; t < 4; ++t) {
            const int kv = kv0 + t * 16 + quad * 4;
#pragma unroll
            for (int g = 0; g < 4; ++g)
              if (kv + g > q) s[qg][t][g] = -1e30f;
          }
        }
      }
      // ---- pure-VALU block: P = exp2(s), l accumulate, pack to bf16 ----
      bf16x4 pa[2][4];
#pragma unroll
      for (int t = 0; t < 4; ++t) {
#pragma unroll
        for (int qg = 0; qg < 2; ++qg) {
#pragma unroll
          for (int g = 0; g < 4; ++g)
            s[qg][t][g] = __builtin_amdgcn_exp2f(s[qg][t][g]);
          lacc[qg] += s[qg][t];
          bf16x4 pk;
#pragma unroll
          for (int g = 0; g < 4; ++g) pk[g] = (bf16)s[qg][t][g];
          pa[qg][t] = pk;
        }
      }
      // ---- pure-MFMA block: PV via 16x16x16 (P from registers) ----
      __builtin_amdgcn_s_setprio(1);
#pragma unroll
      for (int t = 0; t < 4; ++t) {
#pragma unroll
        for (int tn = 0; tn < 4; ++tn) {
          bf16x4 vf = *(const bf16x4*)(
              vb + (tn * 16 + r) * 64 +
              ((2 * t + (quad >> 1)) ^ r7) * 8 + (quad & 1) * 4);
          oacc[0][tn] = mfma16(pa[0][t], vf, oacc[0][tn]);
          oacc[1][tn] = mfma16(pa[1][t], vf, oacc[1][tn]);
        }
      }
      __builtin_amdgcn_s_setprio(0);
    }
    // ONE full drain per tile: next tile landed in LDS, all LDS reads
    // retired, all waves synced. Nothing outstanding crosses this point.
    asm volatile("s_waitcnt vmcnt(0) lgkmcnt(0)\n\ts_barrier" ::: "memory");
  }

  // epilogue: reduce l per q (= lane r) per qg, normalize, store
#pragma unroll
  for (int qg = 0; qg < 2; ++qg) {
    float rs = (lacc[qg][0] + lacc[qg][1]) + (lacc[qg][2] + lacc[qg][3]);
    rs += __shfl_xor(rs, 16, 64);
    rs += __shfl_xor(rs, 32, 64);
    const float inv = 1.f / rs;
    f32x4 ib;
#pragma unroll
    for (int g = 0; g < 4; ++g) ib[g] = __shfl(inv, quad * 4 + g, 64);
#pragma unroll
    for (int tn = 0; tn < 4; ++tn) {
      f32x4 ov = oacc[qg][tn] * ib;
#pragma unroll
      for (int g = 0; g < 4; ++g)
        Ch[(size_t)(q0w + qg * 16 + quad * 4 + g) * DH_ + tn * 16 + r] =
            (bf16)ov[g];
    }
  }
}

// ---------------- LayerNorm in-place on d_out ----------------
__global__ __launch_bounds__(256) void ln_kernel(float* __restrict__ out,
                                                 const float* __restrict__ gamma,
                                                 const float* __restrict__ beta) {
  __shared__ float red[8];
  size_t row = blockIdx.x;
  float* p = out + row * 1024;
  int tid = threadIdx.x;
  float4 v = ((const float4*)p)[tid];
  float s1 = v.x + v.y + v.z + v.w;
  float s2 = v.x * v.x + v.y * v.y + v.z * v.z + v.w * v.w;
#pragma unroll
  for (int o = 1; o < 64; o <<= 1) {
    s1 += __shfl_xor(s1, o, 64);
    s2 += __shfl_xor(s2, o, 64);
  }
  int wave = tid >> 6, lane = tid & 63;
  if (lane == 0) { red[wave] = s1; red[4 + wave] = s2; }
  __syncthreads();
  s1 = red[0] + red[1] + red[2] + red[3];
  s2 = red[4] + red[5] + red[6] + red[7];
  float mean = s1 * (1.f / 1024.f);
  float var = s2 * (1.f / 1024.f) - mean * mean;
  float rstd = rsqrtf(var + 1e-5f);
  float4 g = ((const float4*)gamma)[tid];
  float4 b = ((const float4*)beta)[tid];
  float4 o;
  o.x = (v.x - mean) * rstd * g.x + b.x;
  o.y = (v.y - mean) * rstd * g.y + b.y;
  o.z = (v.z - mean) * rstd * g.z + b.z;
  o.w = (v.w - mean) * rstd * g.w + b.w;
  ((float4*)p)[tid] = o;
}

extern "C" void kernel_launch(void* const* d_in, const int* in_sizes, int n_in,
                              void* d_out, int out_size, void* d_ws,
                              size_t ws_size, hipStream_t stream) {
  (void)in_sizes; (void)n_in; (void)out_size; (void)ws_size;
  const float* x  = (const float*)d_in[0];
  const float* WQ = (const float*)d_in[1];
  const float* WK = (const float*)d_in[2];
  const float* WV = (const float*)d_in[3];
  const float* WO = (const float*)d_in[4];
  const float* gamma = (const float*)d_in[5];
  const float* beta  = (const float*)d_in[6];
  float* out = (float*)d_out;

  bf16* ws = (bf16*)d_ws;
  const size_t MD = (size_t)M_ * D_;
  const size_t WW = (size_t)D_ * D_;
  bf16* xb   = ws;
  bf16* wqt  = xb + MD;
  bf16* wkt  = wqt + WW;
  bf16* wvt  = wkt + WW;
  bf16* wot  = wvt + WW;
  bf16* Qb   = wot + WW;
  bf16* Kb   = Qb + MD;
  bf16* Vtb  = Kb + MD;
  bf16* ctxb = Vtb + MD;

  constexpr int GEMM_LDS = 3 * 48 * 1024;  // 147456 B
  static bool s_attr = false;
  if (!s_attr) {
    s_attr = true;
    (void)hipFuncSetAttribute(reinterpret_cast<const void*>(gemm_kernel<0>),
                              hipFuncAttributeMaxDynamicSharedMemorySize,
                              GEMM_LDS);
    (void)hipFuncSetAttribute(reinterpret_cast<const void*>(gemm_kernel<1>),
                              hipFuncAttributeMaxDynamicSharedMemorySize,
                              GEMM_LDS);
  }

  cvt_all_kernel<<<dim3(8192), dim3(256), 0, stream>>>(
      x, WQ, WK, WV, WO, xb, wqt, wkt, wvt, wot);
  gemm_kernel<0><<<dim3(768), dim3(512), GEMM_LDS, stream>>>(
      xb, wqt, wkt, wvt, Qb, Kb, Vtb, nullptr, nullptr);
  attn_kernel<<<dim3(512), dim3(512), 0, stream>>>(Qb, Kb, Vtb, ctxb);
  gemm_kernel<1><<<dim3(256), dim3(512), GEMM_LDS, stream>>>(
      ctxb, wot, nullptr, nullptr, nullptr, nullptr, nullptr, x, out);
  ln_kernel<<<dim3(8192), dim3(256), 0, stream>>>(out, gamma, beta);
}

// Round 7
// 260.441 us; speedup vs baseline: 1.0077x; 1.0028x over previous
//
#include <hip/hip_runtime.h>
#include <hip/hip_bf16.h>
#include <cstdint>
#include <cstddef>

// B=4, S=2048, D=1024, H=16, DH=64, M = B*S = 8192
#define S_ 2048
#define D_ 1024
#define H_ 16
#define DH_ 64
#define M_ 8192

using bf16 = __bf16;
using bf16x4 = __attribute__((ext_vector_type(4))) __bf16;
using bf16x8 = __attribute__((ext_vector_type(8))) __bf16;
using f32x4 = __attribute__((ext_vector_type(4))) float;
using s16x4 = __attribute__((ext_vector_type(4))) short;

__device__ __forceinline__ void g2lds16(const bf16* g, bf16* l) {
  __builtin_amdgcn_global_load_lds(
      (const __attribute__((address_space(1))) void*)g,
      (__attribute__((address_space(3))) void*)l, 16, 0, 0);
}

// 16x16x16 bf16 MFMA (used by attn PV)
__device__ __forceinline__ f32x4 mfma16(bf16x4 a, bf16x4 b, f32x4 c) {
#if __has_builtin(__builtin_amdgcn_mfma_f32_16x16x16_bf16)
  return __builtin_amdgcn_mfma_f32_16x16x16_bf16(a, b, c, 0, 0, 0);
#elif __has_builtin(__builtin_amdgcn_mfma_f32_16x16x16bf16_1k)
  return __builtin_amdgcn_mfma_f32_16x16x16bf16_1k(
      __builtin_bit_cast(s16x4, a), __builtin_bit_cast(s16x4, b), c, 0, 0, 0);
#else
  f32x4 d;
  asm("v_mfma_f32_16x16x16_bf16 %0, %1, %2, %3"
      : "=v"(d)
      : "v"(a), "v"(b), "v"(c));
  return d;
#endif
}

// ------- fused fp32->bf16 converts: x (blocks 0..4095) + 4 weights^T -------
__global__ __launch_bounds__(256) void cvt_all_kernel(
    const float* __restrict__ x, const float* __restrict__ w0,
    const float* __restrict__ w1, const float* __restrict__ w2,
    const float* __restrict__ w3, bf16* __restrict__ xb,
    bf16* __restrict__ o0, bf16* __restrict__ o1, bf16* __restrict__ o2,
    bf16* __restrict__ o3) {
  __shared__ float tile[32][33];
  int bx = blockIdx.x;
  int tid = threadIdx.x;
  if (bx < 4096) {
    size_t i = ((size_t)bx * 256 + tid) * 8;
    float4 a = *(const float4*)(x + i);
    float4 b = *(const float4*)(x + i + 4);
    bf16x8 o;
    o[0] = (bf16)a.x; o[1] = (bf16)a.y; o[2] = (bf16)a.z; o[3] = (bf16)a.w;
    o[4] = (bf16)b.x; o[5] = (bf16)b.y; o[6] = (bf16)b.z; o[7] = (bf16)b.w;
    *(bf16x8*)(xb + i) = o;
    return;
  }
  int wb = bx - 4096;
  int wsel = wb >> 10; wb &= 1023;
  const float* W; bf16* O;
  switch (wsel) {
    case 0: W = w0; O = o0; break;
    case 1: W = w1; O = o1; break;
    case 2: W = w2; O = o2; break;
    default: W = w3; O = o3; break;
  }
  int n0 = (wb & 31) * 32;
  int k0 = (wb >> 5) * 32;
#pragma unroll
  for (int i = 0; i < 4; ++i) {
    int e = tid + i * 256; int rr = e >> 5, cc = e & 31;
    tile[rr][cc] = W[(size_t)(k0 + rr) * 1024 + n0 + cc];
  }
  __syncthreads();
#pragma unroll
  for (int i = 0; i < 4; ++i) {
    int e = tid + i * 256; int rr = e >> 5, cc = e & 31;
    O[(size_t)(n0 + rr) * 1024 + k0 + cc] = (bf16)tile[cc][rr];
  }
}

// ------- GEMM v5: 128x256 tile, BK=64, 8 waves (2M x 4N, 64x64 each),
// TRIPLE-buffered LDS, prefetch distance 2 K-tiles, vmcnt(6) counted wait
// at tile boundaries only; no mid-tile barrier (round-6 win, ~6.5 us).
template <int MODE>
__global__ __launch_bounds__(512, 2) void gemm_kernel(
    const bf16* __restrict__ A,
    const bf16* __restrict__ Bt0, const bf16* __restrict__ Bt1,
    const bf16* __restrict__ Bt2,
    bf16* __restrict__ Qo, bf16* __restrict__ Ko, bf16* __restrict__ Vto,
    const float* __restrict__ xres, float* __restrict__ out) {
  extern __shared__ float4 smem4[];
  bf16* smem = (bf16*)smem4;  // 3 buffers x 24576 elems (A 8192 + B 16384)

  constexpr int NWG = (MODE == 0) ? 768 : 256;
  constexpr int CPX = NWG / 8;
  constexpr int NBN = (MODE == 0) ? 12 : 4;
  const int wg = ((int)blockIdx.x & 7) * CPX + ((int)blockIdx.x >> 3);
  const int bn = wg % NBN, bm = wg / NBN;

  const bf16* Bt;
  int n0full = 0, wsel = 0;
  if constexpr (MODE == 0) {
    wsel = bn >> 2;
    Bt = (wsel == 0) ? Bt0 : (wsel == 1 ? Bt1 : Bt2);
    n0full = (bn & 3) * 256;
  } else {
    Bt = Bt0;
    n0full = bn * 256;
  }

  const int tid = threadIdx.x;
  const int wave = tid >> 6, lane = tid & 63;
  const int quad = lane >> 4, r = lane & 15;
  const int wm = (wave >> 2) * 64, wn = (wave & 3) * 64;

  // ---- staging setup: 6 x 1KB-slab loads per thread per K-tile ----
  const int lrow = lane >> 3;
  const int lcol = ((lane & 7) ^ lrow) * 8;  // pre-swizzled global chunk
  const int am0 = bm * 128 + wave * 8 + lrow;
  const int am1 = am0 + 64;
  const bf16 *p0, *p1, *p2, *p3, *p4, *p5;
  if constexpr (MODE == 0) {
    p0 = A + (size_t)am0 * 1024 + lcol;
    p1 = A + (size_t)am1 * 1024 + lcol;
  } else {
    p0 = A + (size_t)(am0 >> 11) * (16 * (size_t)S_ * DH_) +
         (size_t)(am0 & 2047) * 64 + lcol;
    p1 = A + (size_t)(am1 >> 11) * (16 * (size_t)S_ * DH_) +
         (size_t)(am1 & 2047) * 64 + lcol;
  }
  const int bnr = n0full + wave * 8 + lrow;
  p2 = Bt + (size_t)bnr * 1024 + lcol;
  p3 = Bt + (size_t)(bnr + 64) * 1024 + lcol;
  p4 = Bt + (size_t)(bnr + 128) * 1024 + lcol;
  p5 = Bt + (size_t)(bnr + 192) * 1024 + lcol;
  constexpr ptrdiff_t dA = (MODE == 0) ? 64 : (ptrdiff_t)S_ * DH_;

  const int oA0 = wave * 512, oA1 = (8 + wave) * 512;
  const int oB0 = 8192 + wave * 512, oB1 = 8192 + (8 + wave) * 512;
  const int oB2 = 8192 + (16 + wave) * 512, oB3 = 8192 + (24 + wave) * 512;

  auto stage = [&](bf16* base) {
    g2lds16(p0, base + oA0); p0 += dA;
    g2lds16(p1, base + oA1); p1 += dA;
    g2lds16(p2, base + oB0); p2 += 64;
    g2lds16(p3, base + oB1); p3 += 64;
    g2lds16(p4, base + oB2); p4 += 64;
    g2lds16(p5, base + oB3); p5 += 64;
  };

  f32x4 acc[4][4];
  const f32x4 zero = {0.f, 0.f, 0.f, 0.f};
#pragma unroll
  for (int i = 0; i < 4; ++i)
#pragma unroll
    for (int j = 0; j < 4; ++j) acc[i][j] = zero;

  const int rw = r & 7;
  const int x0 = (quad ^ rw) * 8;        // k-step 0 chunk position
  const int x1 = ((quad + 4) ^ rw) * 8;  // k-step 1
  const int raB = (wm + r) * 64;
  const int rbB = (wn + r) * 64;

  auto phases = [&](const bf16* buf) {
    const bf16* bA = buf;
    const bf16* bB = buf + 8192;
    bf16x8 af[4], bg[4];
    // ---- phase 1: k 0..31
#pragma unroll
    for (int i = 0; i < 4; ++i)
      af[i] = *(const bf16x8*)(bA + raB + i * 1024 + x0);
#pragma unroll
    for (int j = 0; j < 4; ++j)
      bg[j] = *(const bf16x8*)(bB + rbB + j * 1024 + x0);
    __builtin_amdgcn_s_setprio(1);
#pragma unroll
    for (int i = 0; i < 4; ++i)
#pragma unroll
      for (int j = 0; j < 4; ++j)
        acc[i][j] = __builtin_amdgcn_mfma_f32_16x16x32_bf16(af[i], bg[j],
                                                            acc[i][j], 0, 0, 0);
    __builtin_amdgcn_s_setprio(0);
    // (no mid-tile barrier: same buffer, no hazard)
    // ---- phase 2: k 32..63
#pragma unroll
    for (int i = 0; i < 4; ++i)
      af[i] = *(const bf16x8*)(bA + raB + i * 1024 + x1);
#pragma unroll
    for (int j = 0; j < 4; ++j)
      bg[j] = *(const bf16x8*)(bB + rbB + j * 1024 + x1);
    __builtin_amdgcn_s_setprio(1);
#pragma unroll
    for (int i = 0; i < 4; ++i)
#pragma unroll
      for (int j = 0; j < 4; ++j)
        acc[i][j] = __builtin_amdgcn_mfma_f32_16x16x32_bf16(af[i], bg[j],
                                                            acc[i][j], 0, 0, 0);
    __builtin_amdgcn_s_setprio(0);
  };

  bf16* b0 = smem;
  bf16* b1 = smem + 24576;
  bf16* b2 = smem + 49152;

  stage(b0);
  stage(b1);

#pragma unroll 1
  for (int kt = 0; kt < 15; kt += 3) {
    asm volatile("s_waitcnt vmcnt(6)\n\ts_barrier" ::: "memory");
    stage(b2);                    // tile kt+2
    phases(b0);                   // tile kt
    asm volatile("s_waitcnt vmcnt(6)\n\ts_barrier" ::: "memory");
    stage(b0);                    // tile kt+3
    phases(b1);                   // tile kt+1
    asm volatile("s_waitcnt vmcnt(6)\n\ts_barrier" ::: "memory");
    if (kt < 12) stage(b1);       // tile kt+4 (skip nonexistent tile 16)
    phases(b2);                   // tile kt+2
  }
  asm volatile("s_waitcnt vmcnt(0)\n\ts_barrier" ::: "memory");
  phases(b0);                     // tile 15

  // ---- epilogue ----
  const int mB = bm * 128 + wm + quad * 4;
  if constexpr (MODE == 0) {
    if (wsel < 2) {
      bf16* dst = (wsel == 0) ? Qo : Ko;
#pragma unroll
      for (int i = 0; i < 4; ++i) {
#pragma unroll
        for (int j = 0; j < 4; ++j) {
          int n = n0full + wn + j * 16 + r;
          int h = n >> 6, dh = n & 63;
#pragma unroll
          for (int g = 0; g < 4; ++g) {
            int m = mB + i * 16 + g;
            int b = m >> 11, s = m & 2047;
            dst[((size_t)(b * H_ + h) * S_ + s) * DH_ + dh] =
                (bf16)acc[i][j][g];
          }
        }
      }
    } else {  // V: store transposed [B,H,DH,S]
#pragma unroll
      for (int i = 0; i < 4; ++i) {
        int m = mB + i * 16;
        int b = m >> 11, s = m & 2047;
#pragma unroll
        for (int j = 0; j < 4; ++j) {
          int n = n0full + wn + j * 16 + r;
          int h = n >> 6, dh = n & 63;
          bf16x4 pk;
#pragma unroll
          for (int g = 0; g < 4; ++g) pk[g] = (bf16)acc[i][j][g];
          *(bf16x4*)(Vto + ((size_t)(b * H_ + h) * DH_ + dh) * S_ + s) = pk;
        }
      }
    }
  } else {
#pragma unroll
    for (int i = 0; i < 4; ++i) {
#pragma unroll
      for (int j = 0; j < 4; ++j) {
        int n = bn * 256 + wn + j * 16 + r;
#pragma unroll
        for (int g = 0; g < 4; ++g) {
          int m = mB + i * 16 + g;
          size_t idx = (size_t)m * 1024 + n;
          out[idx] = acc[i][j][g] + xres[idx];
        }
      }
    }
  }
}

// ------ flash attention v11: v9 fused inner loop + 3-buffer counted
// pipeline (depth-2 prefetch). Race-clean count: the ONLY VMEM ops in the
// loop are each wave's 2 global_load_lds per tile (Q loads drained with
// vmcnt(0) before the prologue; stores happen only after the loop). Per
// iter ONE combined wait+barrier: vmcnt(2) => tile kt landed (only tile
// kt+1's 2 ops may remain); lgkmcnt(0) before the barrier => all waves'
// tile-(kt-1) ds_reads retired before its buffer is restaged with kt+2.
// Last iter waits vmcnt(0) (its own tile is the newest staged).
// v10's setprio/phase-split reverted (measured -8%).
__global__ __launch_bounds__(512, 4) void attn_kernel(const bf16* __restrict__ Qb,
                                                      const bf16* __restrict__ Kb,
                                                      const bf16* __restrict__ Vtb,
                                                      bf16* __restrict__ ctx) {
  __shared__ __align__(16) bf16 smK[3][64 * 64];
  __shared__ __align__(16) bf16 smV[3][64 * 64];
  const int bx = blockIdx.x;
  const int bh = bx & 63;
  const int i256 = (bx < 256) ? (7 - (bx >> 6)) : ((bx - 256) >> 6);
  const bf16* Qh = Qb + (size_t)bh * S_ * DH_;
  const bf16* Kh = Kb + (size_t)bh * S_ * DH_;
  const bf16* Vh = Vtb + (size_t)bh * DH_ * S_;
  bf16* Ch = ctx + (size_t)bh * S_ * DH_;
  const int tid = threadIdx.x, wave = tid >> 6, lane = tid & 63;
  const int quad = lane >> 4, r = lane & 15;
  const int r7 = r & 7;
  const int wrow = wave * 8 + (lane >> 3);         // staging row (of 64)
  const int gcol = ((lane & 7) ^ (lane >> 3)) * 8; // source-side XOR swizzle
  const f32x4 zero = {0.f, 0.f, 0.f, 0.f};
  const int xk0 = (quad ^ r7) * 8, xk1 = ((quad + 4) ^ r7) * 8;

  const int q0w = i256 * 256 + wave * 32;
  const int numkt = 4 * i256 + 4;
  const int lastkt = q0w >> 6;  // per-wave: last active tile == mask tile

  bf16x8 qf[2][2];
  const float qsc = 0.125f * 1.44269504f;  // 1/sqrt(64) * log2(e)
#pragma unroll
  for (int qg = 0; qg < 2; ++qg)
#pragma unroll
    for (int hh = 0; hh < 2; ++hh) {
      bf16x8 q = *(const bf16x8*)(Qh + (size_t)(q0w + qg * 16 + r) * DH_ +
                                  hh * 32 + quad * 8);
#pragma unroll
      for (int i = 0; i < 8; ++i) q[i] = (bf16)((float)q[i] * qsc);
      qf[qg][hh] = q;
    }

  f32x4 lacc[2] = {zero, zero};
  f32x4 oacc[2][4];
#pragma unroll
  for (int qg = 0; qg < 2; ++qg)
#pragma unroll
    for (int tn = 0; tn < 4; ++tn) oacc[qg][tn] = zero;

  // drain Q loads so the in-loop vmcnt count is exactly the staging ops
  asm volatile("s_waitcnt vmcnt(0)" ::: "memory");

  auto STAGE = [&](int t, int b) {
    g2lds16(Kh + (size_t)(t * 64 + wrow) * DH_ + gcol, &smK[b][wave * 512]);
    g2lds16(Vh + (size_t)wrow * S_ + t * 64 + gcol, &smV[b][wave * 512]);
  };

  // prologue: depth-2 prefetch (numkt >= 4 always)
  STAGE(0, 0);
  STAGE(1, 1);

  int cur = 0;
#pragma unroll 1
  for (int kt = 0; kt < numkt; ++kt) {
    if (kt + 1 < numkt)
      asm volatile("s_waitcnt vmcnt(2) lgkmcnt(0)\n\ts_barrier" ::: "memory");
    else
      asm volatile("s_waitcnt vmcnt(0) lgkmcnt(0)\n\ts_barrier" ::: "memory");
    if (kt + 2 < numkt) {
      int nb = cur + 2; if (nb >= 3) nb -= 3;
      STAGE(kt + 2, nb);
    }
    if (kt <= lastkt) {  // wave not fully masked for this kv tile
      const int kv0 = kt * 64;
      const bf16* kb = &smK[cur][0];
      const bf16* vb = &smV[cur][0];

      // S^T: s[qg][t][g] = S[kv=kv0+t*16+quad*4+g][q=q0w+qg*16+r]
      f32x4 s[2][4];
#pragma unroll
      for (int t = 0; t < 4; ++t) {
        bf16x8 kf0 = *(const bf16x8*)(kb + (t * 16 + r) * 64 + xk0);
        bf16x8 kf1 = *(const bf16x8*)(kb + (t * 16 + r) * 64 + xk1);
#pragma unroll
        for (int qg = 0; qg < 2; ++qg) {
          f32x4 z = __builtin_amdgcn_mfma_f32_16x16x32_bf16(kf0, qf[qg][0],
                                                            zero, 0, 0, 0);
          s[qg][t] = __builtin_amdgcn_mfma_f32_16x16x32_bf16(kf1, qf[qg][1],
                                                             z, 0, 0, 0);
        }
      }
      if (kt == lastkt) {  // exactly one diagonal tile per wave
#pragma unroll
        for (int qg = 0; qg < 2; ++qg) {
          const int q = q0w + qg * 16 + r;
#pragma unroll
          for (int t = 0; t < 4; ++t) {
            const int kv = kv0 + t * 16 + quad * 4;
#pragma unroll
            for (int g = 0; g < 4; ++g)
              if (kv + g > q) s[qg][t][g] = -1e30f;
          }
        }
      }
      // P = exp2(s); l accumulate; PV via 16x16x16 MFMA (P from registers)
#pragma unroll
      for (int t = 0; t < 4; ++t) {
        bf16x4 pa[2];
#pragma unroll
        for (int qg = 0; qg < 2; ++qg) {
#pragma unroll
          for (int g = 0; g < 4; ++g)
            s[qg][t][g] = __builtin_amdgcn_exp2f(s[qg][t][g]);
          lacc[qg] += s[qg][t];
          bf16x4 pk;
#pragma unroll
          for (int g = 0; g < 4; ++g) pk[g] = (bf16)s[qg][t][g];
          pa[qg] = pk;
        }
#pragma unroll
        for (int tn = 0; tn < 4; ++tn) {
          bf16x4 vf = *(const bf16x4*)(
              vb + (tn * 16 + r) * 64 +
              ((2 * t + (quad >> 1)) ^ r7) * 8 + (quad & 1) * 4);
          oacc[0][tn] = mfma16(pa[0], vf, oacc[0][tn]);
          oacc[1][tn] = mfma16(pa[1], vf, oacc[1][tn]);
        }
      }
    }
    if (++cur == 3) cur = 0;
  }

  // epilogue: reduce l per q (= lane r) per qg, normalize, store
#pragma unroll
  for (int qg = 0; qg < 2; ++qg) {
    float rs = (lacc[qg][0] + lacc[qg][1]) + (lacc[qg][2] + lacc[qg][3]);
    rs += __shfl_xor(rs, 16, 64);
    rs += __shfl_xor(rs, 32, 64);
    const float inv = 1.f / rs;
    f32x4 ib;
#pragma unroll
    for (int g = 0; g < 4; ++g) ib[g] = __shfl(inv, quad * 4 + g, 64);
#pragma unroll
    for (int tn = 0; tn < 4; ++tn) {
      f32x4 ov = oacc[qg][tn] * ib;
#pragma unroll
      for (int g = 0; g < 4; ++g)
        Ch[(size_t)(q0w + qg * 16 + quad * 4 + g) * DH_ + tn * 16 + r] =
            (bf16)ov[g];
    }
  }
}

// ---------------- LayerNorm in-place on d_out ----------------
__global__ __launch_bounds__(256) void ln_kernel(float* __restrict__ out,
                                                 const float* __restrict__ gamma,
                                                 const float* __restrict__ beta) {
  __shared__ float red[8];
  size_t row = blockIdx.x;
  float* p = out + row * 1024;
  int tid = threadIdx.x;
  float4 v = ((const float4*)p)[tid];
  float s1 = v.x + v.y + v.z + v.w;
  float s2 = v.x * v.x + v.y * v.y + v.z * v.z + v.w * v.w;
#pragma unroll
  for (int o = 1; o < 64; o <<= 1) {
    s1 += __shfl_xor(s1, o, 64);
    s2 += __shfl_xor(s2, o, 64);
  }
  int wave = tid >> 6, lane = tid & 63;
  if (lane == 0) { red[wave] = s1; red[4 + wave] = s2; }
  __syncthreads();
  s1 = red[0] + red[1] + red[2] + red[3];
  s2 = red[4] + red[5] + red[6] + red[7];
  float mean = s1 * (1.f / 1024.f);
  float var = s2 * (1.f / 1024.f) - mean * mean;
  float rstd = rsqrtf(var + 1e-5f);
  float4 g = ((const float4*)gamma)[tid];
  float4 b = ((const float4*)beta)[tid];
  float4 o;
  o.x = (v.x - mean) * rstd * g.x + b.x;
  o.y = (v.y - mean) * rstd * g.y + b.y;
  o.z = (v.z - mean) * rstd * g.z + b.z;
  o.w = (v.w - mean) * rstd * g.w + b.w;
  ((float4*)p)[tid] = o;
}

extern "C" void kernel_launch(void* const* d_in, const int* in_sizes, int n_in,
                              void* d_out, int out_size, void* d_ws,
                              size_t ws_size, hipStream_t stream) {
  (void)in_sizes; (void)n_in; (void)out_size; (void)ws_size;
  const float* x  = (const float*)d_in[0];
  const float* WQ = (const float*)d_in[1];
  const float* WK = (const float*)d_in[2];
  const float* WV = (const float*)d_in[3];
  const float* WO = (const float*)d_in[4];
  const float* gamma = (const float*)d_in[5];
  const float* beta  = (const float*)d_in[6];
  float* out = (float*)d_out;

  bf16* ws = (bf16*)d_ws;
  const size_t MD = (size_t)M_ * D_;
  const size_t WW = (size_t)D_ * D_;
  bf16* xb   = ws;
  bf16* wqt  = xb + MD;
  bf16* wkt  = wqt + WW;
  bf16* wvt  = wkt + WW;
  bf16* wot  = wvt + WW;
  bf16* Qb   = wot + WW;
  bf16* Kb   = Qb + MD;
  bf16* Vtb  = Kb + MD;
  bf16* ctxb = Vtb + MD;

  constexpr int GEMM_LDS = 3 * 48 * 1024;  // 147456 B
  static bool s_attr = false;
  if (!s_attr) {
    s_attr = true;
    (void)hipFuncSetAttribute(reinterpret_cast<const void*>(gemm_kernel<0>),
                              hipFuncAttributeMaxDynamicSharedMemorySize,
                              GEMM_LDS);
    (void)hipFuncSetAttribute(reinterpret_cast<const void*>(gemm_kernel<1>),
                              hipFuncAttributeMaxDynamicSharedMemorySize,
                              GEMM_LDS);
  }

  cvt_all_kernel<<<dim3(8192), dim3(256), 0, stream>>>(
      x, WQ, WK, WV, WO, xb, wqt, wkt, wvt, wot);
  gemm_kernel<0><<<dim3(768), dim3(512), GEMM_LDS, stream>>>(
      xb, wqt, wkt, wvt, Qb, Kb, Vtb, nullptr, nullptr);
  attn_kernel<<<dim3(512), dim3(512), 0, stream>>>(Qb, Kb, Vtb, ctxb);
  gemm_kernel<1><<<dim3(256), dim3(512), GEMM_LDS, stream>>>(
      ctxb, wot, nullptr, nullptr, nullptr, nullptr, nullptr, x, out);
  ln_kernel<<<dim3(8192), dim3(256), 0, stream>>>(out, gamma, beta);
}

// Round 8
// 254.324 us; speedup vs baseline: 1.0319x; 1.0241x over previous
//
#include <hip/hip_runtime.h>
#include <hip/hip_bf16.h>
#include <cstdint>
#include <cstddef>

// B=4, S=2048, D=1024, H=16, DH=64, M = B*S = 8192
#define S_ 2048
#define D_ 1024
#define H_ 16
#define DH_ 64
#define M_ 8192

using bf16 = __bf16;
using bf16x4 = __attribute__((ext_vector_type(4))) __bf16;
using bf16x8 = __attribute__((ext_vector_type(8))) __bf16;
using f32x4 = __attribute__((ext_vector_type(4))) float;
using s16x4 = __attribute__((ext_vector_type(4))) short;

__device__ __forceinline__ void g2lds16(const bf16* g, bf16* l) {
  __builtin_amdgcn_global_load_lds(
      (const __attribute__((address_space(1))) void*)g,
      (__attribute__((address_space(3))) void*)l, 16, 0, 0);
}

// 16x16x16 bf16 MFMA (used by attn PV)
__device__ __forceinline__ f32x4 mfma16(bf16x4 a, bf16x4 b, f32x4 c) {
#if __has_builtin(__builtin_amdgcn_mfma_f32_16x16x16_bf16)
  return __builtin_amdgcn_mfma_f32_16x16x16_bf16(a, b, c, 0, 0, 0);
#elif __has_builtin(__builtin_amdgcn_mfma_f32_16x16x16bf16_1k)
  return __builtin_amdgcn_mfma_f32_16x16x16bf16_1k(
      __builtin_bit_cast(s16x4, a), __builtin_bit_cast(s16x4, b), c, 0, 0, 0);
#else
  f32x4 d;
  asm("v_mfma_f32_16x16x16_bf16 %0, %1, %2, %3"
      : "=v"(d)
      : "v"(a), "v"(b), "v"(c));
  return d;
#endif
}

// ------- fused fp32->bf16 converts: x (blocks 0..4095) + 4 weights^T -------
__global__ __launch_bounds__(256) void cvt_all_kernel(
    const float* __restrict__ x, const float* __restrict__ w0,
    const float* __restrict__ w1, const float* __restrict__ w2,
    const float* __restrict__ w3, bf16* __restrict__ xb,
    bf16* __restrict__ o0, bf16* __restrict__ o1, bf16* __restrict__ o2,
    bf16* __restrict__ o3) {
  __shared__ float tile[32][33];
  int bx = blockIdx.x;
  int tid = threadIdx.x;
  if (bx < 4096) {
    size_t i = ((size_t)bx * 256 + tid) * 8;
    float4 a = *(const float4*)(x + i);
    float4 b = *(const float4*)(x + i + 4);
    bf16x8 o;
    o[0] = (bf16)a.x; o[1] = (bf16)a.y; o[2] = (bf16)a.z; o[3] = (bf16)a.w;
    o[4] = (bf16)b.x; o[5] = (bf16)b.y; o[6] = (bf16)b.z; o[7] = (bf16)b.w;
    *(bf16x8*)(xb + i) = o;
    return;
  }
  int wb = bx - 4096;
  int wsel = wb >> 10; wb &= 1023;
  const float* W; bf16* O;
  switch (wsel) {
    case 0: W = w0; O = o0; break;
    case 1: W = w1; O = o1; break;
    case 2: W = w2; O = o2; break;
    default: W = w3; O = o3; break;
  }
  int n0 = (wb & 31) * 32;
  int k0 = (wb >> 5) * 32;
#pragma unroll
  for (int i = 0; i < 4; ++i) {
    int e = tid + i * 256; int rr = e >> 5, cc = e & 31;
    tile[rr][cc] = W[(size_t)(k0 + rr) * 1024 + n0 + cc];
  }
  __syncthreads();
#pragma unroll
  for (int i = 0; i < 4; ++i) {
    int e = tid + i * 256; int rr = e >> 5, cc = e & 31;
    O[(size_t)(n0 + rr) * 1024 + k0 + cc] = (bf16)tile[cc][rr];
  }
}

// ------- GEMM v5: 128x256 tile, BK=64, 8 waves (2M x 4N, 64x64 each),
// TRIPLE-buffered LDS, prefetch distance 2 K-tiles, vmcnt(6) counted wait
// at tile boundaries only; no mid-tile barrier (round-6 win).
// (unchanged; multiple clean verified runs)
template <int MODE>
__global__ __launch_bounds__(512, 2) void gemm_kernel(
    const bf16* __restrict__ A,
    const bf16* __restrict__ Bt0, const bf16* __restrict__ Bt1,
    const bf16* __restrict__ Bt2,
    bf16* __restrict__ Qo, bf16* __restrict__ Ko, bf16* __restrict__ Vto,
    const float* __restrict__ xres, float* __restrict__ out) {
  extern __shared__ float4 smem4[];
  bf16* smem = (bf16*)smem4;  // 3 buffers x 24576 elems (A 8192 + B 16384)

  constexpr int NWG = (MODE == 0) ? 768 : 256;
  constexpr int CPX = NWG / 8;
  constexpr int NBN = (MODE == 0) ? 12 : 4;
  const int wg = ((int)blockIdx.x & 7) * CPX + ((int)blockIdx.x >> 3);
  const int bn = wg % NBN, bm = wg / NBN;

  const bf16* Bt;
  int n0full = 0, wsel = 0;
  if constexpr (MODE == 0) {
    wsel = bn >> 2;
    Bt = (wsel == 0) ? Bt0 : (wsel == 1 ? Bt1 : Bt2);
    n0full = (bn & 3) * 256;
  } else {
    Bt = Bt0;
    n0full = bn * 256;
  }

  const int tid = threadIdx.x;
  const int wave = tid >> 6, lane = tid & 63;
  const int quad = lane >> 4, r = lane & 15;
  const int wm = (wave >> 2) * 64, wn = (wave & 3) * 64;

  // ---- staging setup: 6 x 1KB-slab loads per thread per K-tile ----
  const int lrow = lane >> 3;
  const int lcol = ((lane & 7) ^ lrow) * 8;  // pre-swizzled global chunk
  const int am0 = bm * 128 + wave * 8 + lrow;
  const int am1 = am0 + 64;
  const bf16 *p0, *p1, *p2, *p3, *p4, *p5;
  if constexpr (MODE == 0) {
    p0 = A + (size_t)am0 * 1024 + lcol;
    p1 = A + (size_t)am1 * 1024 + lcol;
  } else {
    p0 = A + (size_t)(am0 >> 11) * (16 * (size_t)S_ * DH_) +
         (size_t)(am0 & 2047) * 64 + lcol;
    p1 = A + (size_t)(am1 >> 11) * (16 * (size_t)S_ * DH_) +
         (size_t)(am1 & 2047) * 64 + lcol;
  }
  const int bnr = n0full + wave * 8 + lrow;
  p2 = Bt + (size_t)bnr * 1024 + lcol;
  p3 = Bt + (size_t)(bnr + 64) * 1024 + lcol;
  p4 = Bt + (size_t)(bnr + 128) * 1024 + lcol;
  p5 = Bt + (size_t)(bnr + 192) * 1024 + lcol;
  constexpr ptrdiff_t dA = (MODE == 0) ? 64 : (ptrdiff_t)S_ * DH_;

  const int oA0 = wave * 512, oA1 = (8 + wave) * 512;
  const int oB0 = 8192 + wave * 512, oB1 = 8192 + (8 + wave) * 512;
  const int oB2 = 8192 + (16 + wave) * 512, oB3 = 8192 + (24 + wave) * 512;

  auto stage = [&](bf16* base) {
    g2lds16(p0, base + oA0); p0 += dA;
    g2lds16(p1, base + oA1); p1 += dA;
    g2lds16(p2, base + oB0); p2 += 64;
    g2lds16(p3, base + oB1); p3 += 64;
    g2lds16(p4, base + oB2); p4 += 64;
    g2lds16(p5, base + oB3); p5 += 64;
  };

  f32x4 acc[4][4];
  const f32x4 zero = {0.f, 0.f, 0.f, 0.f};
#pragma unroll
  for (int i = 0; i < 4; ++i)
#pragma unroll
    for (int j = 0; j < 4; ++j) acc[i][j] = zero;

  const int rw = r & 7;
  const int x0 = (quad ^ rw) * 8;        // k-step 0 chunk position
  const int x1 = ((quad + 4) ^ rw) * 8;  // k-step 1
  const int raB = (wm + r) * 64;
  const int rbB = (wn + r) * 64;

  auto phases = [&](const bf16* buf) {
    const bf16* bA = buf;
    const bf16* bB = buf + 8192;
    bf16x8 af[4], bg[4];
    // ---- phase 1: k 0..31
#pragma unroll
    for (int i = 0; i < 4; ++i)
      af[i] = *(const bf16x8*)(bA + raB + i * 1024 + x0);
#pragma unroll
    for (int j = 0; j < 4; ++j)
      bg[j] = *(const bf16x8*)(bB + rbB + j * 1024 + x0);
    __builtin_amdgcn_s_setprio(1);
#pragma unroll
    for (int i = 0; i < 4; ++i)
#pragma unroll
      for (int j = 0; j < 4; ++j)
        acc[i][j] = __builtin_amdgcn_mfma_f32_16x16x32_bf16(af[i], bg[j],
                                                            acc[i][j], 0, 0, 0);
    __builtin_amdgcn_s_setprio(0);
    // (no mid-tile barrier: same buffer, no hazard)
    // ---- phase 2: k 32..63
#pragma unroll
    for (int i = 0; i < 4; ++i)
      af[i] = *(const bf16x8*)(bA + raB + i * 1024 + x1);
#pragma unroll
    for (int j = 0; j < 4; ++j)
      bg[j] = *(const bf16x8*)(bB + rbB + j * 1024 + x1);
    __builtin_amdgcn_s_setprio(1);
#pragma unroll
    for (int i = 0; i < 4; ++i)
#pragma unroll
      for (int j = 0; j < 4; ++j)
        acc[i][j] = __builtin_amdgcn_mfma_f32_16x16x32_bf16(af[i], bg[j],
                                                            acc[i][j], 0, 0, 0);
    __builtin_amdgcn_s_setprio(0);
  };

  bf16* b0 = smem;
  bf16* b1 = smem + 24576;
  bf16* b2 = smem + 49152;

  stage(b0);
  stage(b1);

#pragma unroll 1
  for (int kt = 0; kt < 15; kt += 3) {
    asm volatile("s_waitcnt vmcnt(6)\n\ts_barrier" ::: "memory");
    stage(b2);                    // tile kt+2
    phases(b0);                   // tile kt
    asm volatile("s_waitcnt vmcnt(6)\n\ts_barrier" ::: "memory");
    stage(b0);                    // tile kt+3
    phases(b1);                   // tile kt+1
    asm volatile("s_waitcnt vmcnt(6)\n\ts_barrier" ::: "memory");
    if (kt < 12) stage(b1);       // tile kt+4 (skip nonexistent tile 16)
    phases(b2);                   // tile kt+2
  }
  asm volatile("s_waitcnt vmcnt(0)\n\ts_barrier" ::: "memory");
  phases(b0);                     // tile 15

  // ---- epilogue ----
  const int mB = bm * 128 + wm + quad * 4;
  if constexpr (MODE == 0) {
    if (wsel < 2) {
      bf16* dst = (wsel == 0) ? Qo : Ko;
#pragma unroll
      for (int i = 0; i < 4; ++i) {
#pragma unroll
        for (int j = 0; j < 4; ++j) {
          int n = n0full + wn + j * 16 + r;
          int h = n >> 6, dh = n & 63;
#pragma unroll
          for (int g = 0; g < 4; ++g) {
            int m = mB + i * 16 + g;
            int b = m >> 11, s = m & 2047;
            dst[((size_t)(b * H_ + h) * S_ + s) * DH_ + dh] =
                (bf16)acc[i][j][g];
          }
        }
      }
    } else {  // V: store transposed [B,H,DH,S]
#pragma unroll
      for (int i = 0; i < 4; ++i) {
        int m = mB + i * 16;
        int b = m >> 11, s = m & 2047;
#pragma unroll
        for (int j = 0; j < 4; ++j) {
          int n = n0full + wn + j * 16 + r;
          int h = n >> 6, dh = n & 63;
          bf16x4 pk;
#pragma unroll
          for (int g = 0; g < 4; ++g) pk[g] = (bf16)acc[i][j][g];
          *(bf16x4*)(Vto + ((size_t)(b * H_ + h) * DH_ + dh) * S_ + s) = pk;
        }
      }
    }
  } else {
#pragma unroll
    for (int i = 0; i < 4; ++i) {
#pragma unroll
      for (int j = 0; j < 4; ++j) {
        int n = bn * 256 + wn + j * 16 + r;
#pragma unroll
        for (int g = 0; g < 4; ++g) {
          int m = mB + i * 16 + g;
          size_t idx = (size_t)m * 1024 + n;
          out[idx] = acc[i][j][g] + xres[idx];
        }
      }
    }
  }
}

// ------ flash attention v12: v9 structure with 128-kv SYNC UNITS ------
// Round-7 post-mortem: all sync variants (v6/v8/v9/v11) pin at ~64 us;
// load latency was never exposed (prefetch cover >> latency). The
// recurring cost is per-64-kv overhead: 2 barrier crossings, waits, loop
// control, address re-derivation. v12 halves it: each unit = 2 kv-64
// subtiles. Per unit: {stage next unit (4 loads, into the non-read
// buffer) -> compute subtile 2u -> compute 2u+1 -> one vmcnt(0)
// lgkmcnt(0)+barrier}. Ordering is v9's proven scheme at coarser grain:
// the end-of-unit barrier that protected buffer reuse still does; the
// stage target buffer's old data was fully read before the previous
// barrier. LDS 2buf x 2sub x (8K+8V) KB = 64KB/block, 2 blocks/CU.
__global__ __launch_bounds__(512, 4) void attn_kernel(const bf16* __restrict__ Qb,
                                                      const bf16* __restrict__ Kb,
                                                      const bf16* __restrict__ Vtb,
                                                      bf16* __restrict__ ctx) {
  __shared__ __align__(16) bf16 smK[2][2][64 * 64];
  __shared__ __align__(16) bf16 smV[2][2][64 * 64];
  const int bx = blockIdx.x;
  const int bh = bx & 63;
  const int i256 = (bx < 256) ? (7 - (bx >> 6)) : ((bx - 256) >> 6);
  const bf16* Qh = Qb + (size_t)bh * S_ * DH_;
  const bf16* Kh = Kb + (size_t)bh * S_ * DH_;
  const bf16* Vh = Vtb + (size_t)bh * DH_ * S_;
  bf16* Ch = ctx + (size_t)bh * S_ * DH_;
  const int tid = threadIdx.x, wave = tid >> 6, lane = tid & 63;
  const int quad = lane >> 4, r = lane & 15;
  const int r7 = r & 7;
  const int wrow = wave * 8 + (lane >> 3);         // staging row (of 64)
  const int gcol = ((lane & 7) ^ (lane >> 3)) * 8; // source-side XOR swizzle
  const f32x4 zero = {0.f, 0.f, 0.f, 0.f};
  const int xk0 = (quad ^ r7) * 8, xk1 = ((quad + 4) ^ r7) * 8;

  const int q0w = i256 * 256 + wave * 32;
  const int numkt = 4 * i256 + 4;   // always even
  const int NU = numkt >> 1;        // 128-kv units
  const int lastkt = q0w >> 6;      // per-wave: last active tile == mask tile

  bf16x8 qf[2][2];
  const float qsc = 0.125f * 1.44269504f;  // 1/sqrt(64) * log2(e)
#pragma unroll
  for (int qg = 0; qg < 2; ++qg)
#pragma unroll
    for (int hh = 0; hh < 2; ++hh) {
      bf16x8 q = *(const bf16x8*)(Qh + (size_t)(q0w + qg * 16 + r) * DH_ +
                                  hh * 32 + quad * 8);
#pragma unroll
      for (int i = 0; i < 8; ++i) q[i] = (bf16)((float)q[i] * qsc);
      qf[qg][hh] = q;
    }

  f32x4 lacc[2] = {zero, zero};
  f32x4 oacc[2][4];
#pragma unroll
  for (int qg = 0; qg < 2; ++qg)
#pragma unroll
    for (int tn = 0; tn < 4; ++tn) oacc[qg][tn] = zero;

  auto STAGE = [&](int u, int b) {  // stage both subtiles of unit u
#pragma unroll
    for (int sub = 0; sub < 2; ++sub) {
      const int kt = 2 * u + sub;
      g2lds16(Kh + (size_t)(kt * 64 + wrow) * DH_ + gcol,
              &smK[b][sub][wave * 512]);
      g2lds16(Vh + (size_t)wrow * S_ + kt * 64 + gcol,
              &smV[b][sub][wave * 512]);
    }
  };

  // prologue: unit 0 -> buffer 0, full drain (also drains Q loads)
  STAGE(0, 0);
  asm volatile("s_waitcnt vmcnt(0)\n\ts_barrier" ::: "memory");

#pragma unroll 1
  for (int u = 0; u < NU; ++u) {
    const int b = u & 1;
    if (u + 1 < NU) STAGE(u + 1, b ^ 1);  // lands in non-read buffer
#pragma unroll
    for (int sub = 0; sub < 2; ++sub) {
      const int kt = 2 * u + sub;
      if (kt <= lastkt) {  // wave not fully masked for this kv subtile
        const int kv0 = kt * 64;
        const bf16* kb = &smK[b][sub][0];
        const bf16* vb = &smV[b][sub][0];

        // S^T: s[qg][t][g] = S[kv=kv0+t*16+quad*4+g][q=q0w+qg*16+r]
        f32x4 s[2][4];
#pragma unroll
        for (int t = 0; t < 4; ++t) {
          bf16x8 kf0 = *(const bf16x8*)(kb + (t * 16 + r) * 64 + xk0);
          bf16x8 kf1 = *(const bf16x8*)(kb + (t * 16 + r) * 64 + xk1);
#pragma unroll
          for (int qg = 0; qg < 2; ++qg) {
            f32x4 z = __builtin_amdgcn_mfma_f32_16x16x32_bf16(kf0, qf[qg][0],
                                                              zero, 0, 0, 0);
            s[qg][t] = __builtin_amdgcn_mfma_f32_16x16x32_bf16(kf1, qf[qg][1],
                                                               z, 0, 0, 0);
          }
        }
        if (kt == lastkt) {  // exactly one diagonal subtile per wave
#pragma unroll
          for (int qg = 0; qg < 2; ++qg) {
            const int q = q0w + qg * 16 + r;
#pragma unroll
            for (int t = 0; t < 4; ++t) {
              const int kv = kv0 + t * 16 + quad * 4;
#pragma unroll
              for (int g = 0; g < 4; ++g)
                if (kv + g > q) s[qg][t][g] = -1e30f;
            }
          }
        }
        // P = exp2(s); l accumulate; PV via 16x16x16 MFMA (P in registers)
#pragma unroll
        for (int t = 0; t < 4; ++t) {
          bf16x4 pa[2];
#pragma unroll
          for (int qg = 0; qg < 2; ++qg) {
#pragma unroll
            for (int g = 0; g < 4; ++g)
              s[qg][t][g] = __builtin_amdgcn_exp2f(s[qg][t][g]);
            lacc[qg] += s[qg][t];
            bf16x4 pk;
#pragma unroll
            for (int g = 0; g < 4; ++g) pk[g] = (bf16)s[qg][t][g];
            pa[qg] = pk;
          }
#pragma unroll
          for (int tn = 0; tn < 4; ++tn) {
            bf16x4 vf = *(const bf16x4*)(
                vb + (tn * 16 + r) * 64 +
                ((2 * t + (quad >> 1)) ^ r7) * 8 + (quad & 1) * 4);
            oacc[0][tn] = mfma16(pa[0], vf, oacc[0][tn]);
            oacc[1][tn] = mfma16(pa[1], vf, oacc[1][tn]);
          }
        }
      }
    }
    // ONE drain per 128 kv: next unit landed (issued ~2 subtile-computes
    // ago), all LDS reads retired, all waves synced.
    asm volatile("s_waitcnt vmcnt(0) lgkmcnt(0)\n\ts_barrier" ::: "memory");
  }

  // epilogue: reduce l per q (= lane r) per qg, normalize, store
#pragma unroll
  for (int qg = 0; qg < 2; ++qg) {
    float rs = (lacc[qg][0] + lacc[qg][1]) + (lacc[qg][2] + lacc[qg][3]);
    rs += __shfl_xor(rs, 16, 64);
    rs += __shfl_xor(rs, 32, 64);
    const float inv = 1.f / rs;
    f32x4 ib;
#pragma unroll
    for (int g = 0; g < 4; ++g) ib[g] = __shfl(inv, quad * 4 + g, 64);
#pragma unroll
    for (int tn = 0; tn < 4; ++tn) {
      f32x4 ov = oacc[qg][tn] * ib;
#pragma unroll
      for (int g = 0; g < 4; ++g)
        Ch[(size_t)(q0w + qg * 16 + quad * 4 + g) * DH_ + tn * 16 + r] =
            (bf16)ov[g];
    }
  }
}

// ---------------- LayerNorm in-place on d_out ----------------
__global__ __launch_bounds__(256) void ln_kernel(float* __restrict__ out,
                                                 const float* __restrict__ gamma,
                                                 const float* __restrict__ beta) {
  __shared__ float red[8];
  size_t row = blockIdx.x;
  float* p = out + row * 1024;
  int tid = threadIdx.x;
  float4 v = ((const float4*)p)[tid];
  float s1 = v.x + v.y + v.z + v.w;
  float s2 = v.x * v.x + v.y * v.y + v.z * v.z + v.w * v.w;
#pragma unroll
  for (int o = 1; o < 64; o <<= 1) {
    s1 += __shfl_xor(s1, o, 64);
    s2 += __shfl_xor(s2, o, 64);
  }
  int wave = tid >> 6, lane = tid & 63;
  if (lane == 0) { red[wave] = s1; red[4 + wave] = s2; }
  __syncthreads();
  s1 = red[0] + red[1] + red[2] + red[3];
  s2 = red[4] + red[5] + red[6] + red[7];
  float mean = s1 * (1.f / 1024.f);
  float var = s2 * (1.f / 1024.f) - mean * mean;
  float rstd = rsqrtf(var + 1e-5f);
  float4 g = ((const float4*)gamma)[tid];
  float4 b = ((const float4*)beta)[tid];
  float4 o;
  o.x = (v.x - mean) * rstd * g.x + b.x;
  o.y = (v.y - mean) * rstd * g.y + b.y;
  o.z = (v.z - mean) * rstd * g.z + b.z;
  o.w = (v.w - mean) * rstd * g.w + b.w;
  ((float4*)p)[tid] = o;
}

extern "C" void kernel_launch(void* const* d_in, const int* in_sizes, int n_in,
                              void* d_out, int out_size, void* d_ws,
                              size_t ws_size, hipStream_t stream) {
  (void)in_sizes; (void)n_in; (void)out_size; (void)ws_size;
  const float* x  = (const float*)d_in[0];
  const float* WQ = (const float*)d_in[1];
  const float* WK = (const float*)d_in[2];
  const float* WV = (const float*)d_in[3];
  const float* WO = (const float*)d_in[4];
  const float* gamma = (const float*)d_in[5];
  const float* beta  = (const float*)d_in[6];
  float* out = (float*)d_out;

  bf16* ws = (bf16*)d_ws;
  const size_t MD = (size_t)M_ * D_;
  const size_t WW = (size_t)D_ * D_;
  bf16* xb   = ws;
  bf16* wqt  = xb + MD;
  bf16* wkt  = wqt + WW;
  bf16* wvt  = wkt + WW;
  bf16* wot  = wvt + WW;
  bf16* Qb   = wot + WW;
  bf16* Kb   = Qb + MD;
  bf16* Vtb  = Kb + MD;
  bf16* ctxb = Vtb + MD;

  constexpr int GEMM_LDS = 3 * 48 * 1024;  // 147456 B
  static bool s_attr = false;
  if (!s_attr) {
    s_attr = true;
    (void)hipFuncSetAttribute(reinterpret_cast<const void*>(gemm_kernel<0>),
                              hipFuncAttributeMaxDynamicSharedMemorySize,
                              GEMM_LDS);
    (void)hipFuncSetAttribute(reinterpret_cast<const void*>(gemm_kernel<1>),
                              hipFuncAttributeMaxDynamicSharedMemorySize,
                              GEMM_LDS);
  }

  cvt_all_kernel<<<dim3(8192), dim3(256), 0, stream>>>(
      x, WQ, WK, WV, WO, xb, wqt, wkt, wvt, wot);
  gemm_kernel<0><<<dim3(768), dim3(512), GEMM_LDS, stream>>>(
      xb, wqt, wkt, wvt, Qb, Kb, Vtb, nullptr, nullptr);
  attn_kernel<<<dim3(512), dim3(512), 0, stream>>>(Qb, Kb, Vtb, ctxb);
  gemm_kernel<1><<<dim3(256), dim3(512), GEMM_LDS, stream>>>(
      ctxb, wot, nullptr, nullptr, nullptr, nullptr, nullptr, x, out);
  ln_kernel<<<dim3(8192), dim3(256), 0, stream>>>(out, gamma, beta);
}

// Round 9
// 248.701 us; speedup vs baseline: 1.0553x; 1.0226x over previous
//
#include <hip/hip_runtime.h>
#include <hip/hip_bf16.h>
#include <cstdint>
#include <cstddef>

// B=4, S=2048, D=1024, H=16, DH=64, M = B*S = 8192
#define S_ 2048
#define D_ 1024
#define H_ 16
#define DH_ 64
#define M_ 8192

using bf16 = __bf16;
using bf16x4 = __attribute__((ext_vector_type(4))) __bf16;
using bf16x8 = __attribute__((ext_vector_type(8))) __bf16;
using f32x4 = __attribute__((ext_vector_type(4))) float;
using s16x4 = __attribute__((ext_vector_type(4))) short;

__device__ __forceinline__ void g2lds16(const bf16* g, bf16* l) {
  __builtin_amdgcn_global_load_lds(
      (const __attribute__((address_space(1))) void*)g,
      (__attribute__((address_space(3))) void*)l, 16, 0, 0);
}

// 16x16x16 bf16 MFMA (used by attn PV)
__device__ __forceinline__ f32x4 mfma16(bf16x4 a, bf16x4 b, f32x4 c) {
#if __has_builtin(__builtin_amdgcn_mfma_f32_16x16x16_bf16)
  return __builtin_amdgcn_mfma_f32_16x16x16_bf16(a, b, c, 0, 0, 0);
#elif __has_builtin(__builtin_amdgcn_mfma_f32_16x16x16bf16_1k)
  return __builtin_amdgcn_mfma_f32_16x16x16bf16_1k(
      __builtin_bit_cast(s16x4, a), __builtin_bit_cast(s16x4, b), c, 0, 0, 0);
#else
  f32x4 d;
  asm("v_mfma_f32_16x16x16_bf16 %0, %1, %2, %3"
      : "=v"(d)
      : "v"(a), "v"(b), "v"(c));
  return d;
#endif
}

// ------- fused fp32->bf16 converts: x (blocks 0..4095) + 4 weights^T -------
__global__ __launch_bounds__(256) void cvt_all_kernel(
    const float* __restrict__ x, const float* __restrict__ w0,
    const float* __restrict__ w1, const float* __restrict__ w2,
    const float* __restrict__ w3, bf16* __restrict__ xb,
    bf16* __restrict__ o0, bf16* __restrict__ o1, bf16* __restrict__ o2,
    bf16* __restrict__ o3) {
  __shared__ float tile[32][33];
  int bx = blockIdx.x;
  int tid = threadIdx.x;
  if (bx < 4096) {
    size_t i = ((size_t)bx * 256 + tid) * 8;
    float4 a = *(const float4*)(x + i);
    float4 b = *(const float4*)(x + i + 4);
    bf16x8 o;
    o[0] = (bf16)a.x; o[1] = (bf16)a.y; o[2] = (bf16)a.z; o[3] = (bf16)a.w;
    o[4] = (bf16)b.x; o[5] = (bf16)b.y; o[6] = (bf16)b.z; o[7] = (bf16)b.w;
    *(bf16x8*)(xb + i) = o;
    return;
  }
  int wb = bx - 4096;
  int wsel = wb >> 10; wb &= 1023;
  const float* W; bf16* O;
  switch (wsel) {
    case 0: W = w0; O = o0; break;
    case 1: W = w1; O = o1; break;
    case 2: W = w2; O = o2; break;
    default: W = w3; O = o3; break;
  }
  int n0 = (wb & 31) * 32;
  int k0 = (wb >> 5) * 32;
#pragma unroll
  for (int i = 0; i < 4; ++i) {
    int e = tid + i * 256; int rr = e >> 5, cc = e & 31;
    tile[rr][cc] = W[(size_t)(k0 + rr) * 1024 + n0 + cc];
  }
  __syncthreads();
#pragma unroll
  for (int i = 0; i < 4; ++i) {
    int e = tid + i * 256; int rr = e >> 5, cc = e & 31;
    O[(size_t)(n0 + rr) * 1024 + k0 + cc] = (bf16)tile[cc][rr];
  }
}

// ------- GEMM v6: 128x256 tile, BK=32 (round-9 change), 8 waves
// (2M x 4N, 64x64 each), TRIPLE-buffered LDS 3 x 24KB = 72KB ->
// 2 BLOCKS/CU (4 waves/SIMD, double the latency hiding of v5's 1
// block/CU). Per K-tile: single phase (8 ds_read_b128 + 16 MFMA),
// 3 staged loads/thread, counted vmcnt(3) at boundaries (prefetch
// distance 2 tiles; never 0 until the tail). Same proven sync scheme
// as v4/v5, x3-unrolled rotation (30 tiles) + 2-tile tail.
template <int MODE>
__global__ __launch_bounds__(512, 4) void gemm_kernel(
    const bf16* __restrict__ A,
    const bf16* __restrict__ Bt0, const bf16* __restrict__ Bt1,
    const bf16* __restrict__ Bt2,
    bf16* __restrict__ Qo, bf16* __restrict__ Ko, bf16* __restrict__ Vto,
    const float* __restrict__ xres, float* __restrict__ out) {
  extern __shared__ float4 smem4[];
  bf16* smem = (bf16*)smem4;  // 3 buffers x 12288 elems (A 4096 + B 8192)

  constexpr int NWG = (MODE == 0) ? 768 : 256;
  constexpr int CPX = NWG / 8;
  constexpr int NBN = (MODE == 0) ? 12 : 4;
  const int wg = ((int)blockIdx.x & 7) * CPX + ((int)blockIdx.x >> 3);
  const int bn = wg % NBN, bm = wg / NBN;

  const bf16* Bt;
  int n0full = 0, wsel = 0;
  if constexpr (MODE == 0) {
    wsel = bn >> 2;
    Bt = (wsel == 0) ? Bt0 : (wsel == 1 ? Bt1 : Bt2);
    n0full = (bn & 3) * 256;
  } else {
    Bt = Bt0;
    n0full = bn * 256;
  }

  const int tid = threadIdx.x;
  const int wave = tid >> 6, lane = tid & 63;
  const int quad = lane >> 4, r = lane & 15;
  const int wm = (wave >> 2) * 64, wn = (wave & 3) * 64;

  // ---- staging: rows of 32 elems (64B = 4 chunks of 16B); 16 rows/wave.
  // lane l -> row l>>2, LDS chunk l&3, global chunk (l&3)^((l>>2)&3)
  // (pre-swizzled source; LDS linear for global_load_lds).
  const int lrow = lane >> 2;                       // 0..15
  const int lcol = ((lane & 3) ^ (lrow & 3)) * 8;   // elements
  const int am = bm * 128 + wave * 16 + lrow;       // A row (128/block)
  const bf16 *pA, *pB1, *pB2;
  if constexpr (MODE == 0) {
    pA = A + (size_t)am * 1024 + lcol;
  } else {
    // A is ctx [B,H,S,DH]; K-tile kt: head kt>>1, dh (kt&1)*32.
    pA = A + (size_t)(am >> 11) * (16 * (size_t)S_ * DH_) +
         (size_t)(am & 2047) * 64 + lcol;
  }
  const int bnr = n0full + wave * 16 + lrow;
  pB1 = Bt + (size_t)bnr * 1024 + lcol;
  pB2 = Bt + (size_t)(bnr + 128) * 1024 + lcol;
  // MODE1 A-delta alternates +32 (dh 0->32) / +S*DH-32 (next head);
  // branchless toggle d = S*DH - d with S*DH = 64 for MODE0 (always 32).
  constexpr ptrdiff_t dSum = (MODE == 0) ? 64 : (ptrdiff_t)S_ * DH_;
  ptrdiff_t dTog = 32;

  const int oA = wave * 512;           // wave*16 rows * 32 elems
  const int oB1 = 4096 + wave * 512;   // B rows 0..127
  const int oB2 = 8192 + wave * 512;   // B rows 128..255

  auto stage = [&](bf16* base) {
    g2lds16(pA, base + oA);
    g2lds16(pB1, base + oB1);
    g2lds16(pB2, base + oB2);
    pA += dTog; dTog = dSum - dTog;
    pB1 += 32; pB2 += 32;
  };

  f32x4 acc[4][4];
  const f32x4 zero = {0.f, 0.f, 0.f, 0.f};
#pragma unroll
  for (int i = 0; i < 4; ++i)
#pragma unroll
    for (int j = 0; j < 4; ++j) acc[i][j] = zero;

  // reader: row&3 == r&3 for all frag rows (wm/wn/i*16 are mult of 4)
  const int x0 = (quad ^ (r & 3)) * 8;
  const int raB = (wm + r) * 32;
  const int rbB = (wn + r) * 32;

  auto phase = [&](const bf16* buf) {
    const bf16* bA = buf;
    const bf16* bB = buf + 4096;
    bf16x8 af[4], bg[4];
#pragma unroll
    for (int i = 0; i < 4; ++i)
      af[i] = *(const bf16x8*)(bA + raB + i * 512 + x0);
#pragma unroll
    for (int j = 0; j < 4; ++j)
      bg[j] = *(const bf16x8*)(bB + rbB + j * 512 + x0);
    __builtin_amdgcn_s_setprio(1);
#pragma unroll
    for (int i = 0; i < 4; ++i)
#pragma unroll
      for (int j = 0; j < 4; ++j)
        acc[i][j] = __builtin_amdgcn_mfma_f32_16x16x32_bf16(af[i], bg[j],
                                                            acc[i][j], 0, 0, 0);
    __builtin_amdgcn_s_setprio(0);
  };

  bf16* b0 = smem;
  bf16* b1 = smem + 12288;
  bf16* b2 = smem + 24576;

  stage(b0);  // tile 0
  stage(b1);  // tile 1

  // K = 1024 -> 32 tiles of 32. Boundary of tile t: vmcnt(3) (tile t
  // landed; tile t+1's 3 loads stay in flight), then stage tile t+2.
#pragma unroll 1
  for (int kt = 0; kt < 30; kt += 3) {
    asm volatile("s_waitcnt vmcnt(3)\n\ts_barrier" ::: "memory");
    stage(b2);                    // tile kt+2
    phase(b0);                    // tile kt
    asm volatile("s_waitcnt vmcnt(3)\n\ts_barrier" ::: "memory");
    stage(b0);                    // tile kt+3
    phase(b1);                    // tile kt+1
    asm volatile("s_waitcnt vmcnt(3)\n\ts_barrier" ::: "memory");
    stage(b1);                    // tile kt+4
    phase(b2);                    // tile kt+2
  }
  // tail: tiles 30 (b0), 31 (b1) already staged
  asm volatile("s_waitcnt vmcnt(3)\n\ts_barrier" ::: "memory");
  phase(b0);                      // tile 30
  asm volatile("s_waitcnt vmcnt(0)\n\ts_barrier" ::: "memory");
  phase(b1);                      // tile 31

  // ---- epilogue ----
  const int mB = bm * 128 + wm + quad * 4;
  if constexpr (MODE == 0) {
    if (wsel < 2) {
      bf16* dst = (wsel == 0) ? Qo : Ko;
#pragma unroll
      for (int i = 0; i < 4; ++i) {
#pragma unroll
        for (int j = 0; j < 4; ++j) {
          int n = n0full + wn + j * 16 + r;
          int h = n >> 6, dh = n & 63;
#pragma unroll
          for (int g = 0; g < 4; ++g) {
            int m = mB + i * 16 + g;
            int b = m >> 11, s = m & 2047;
            dst[((size_t)(b * H_ + h) * S_ + s) * DH_ + dh] =
                (bf16)acc[i][j][g];
          }
        }
      }
    } else {  // V: store transposed [B,H,DH,S]
#pragma unroll
      for (int i = 0; i < 4; ++i) {
        int m = mB + i * 16;
        int b = m >> 11, s = m & 2047;
#pragma unroll
        for (int j = 0; j < 4; ++j) {
          int n = n0full + wn + j * 16 + r;
          int h = n >> 6, dh = n & 63;
          bf16x4 pk;
#pragma unroll
          for (int g = 0; g < 4; ++g) pk[g] = (bf16)acc[i][j][g];
          *(bf16x4*)(Vto + ((size_t)(b * H_ + h) * DH_ + dh) * S_ + s) = pk;
        }
      }
    }
  } else {
#pragma unroll
    for (int i = 0; i < 4; ++i) {
#pragma unroll
      for (int j = 0; j < 4; ++j) {
        int n = bn * 256 + wn + j * 16 + r;
#pragma unroll
        for (int g = 0; g < 4; ++g) {
          int m = mB + i * 16 + g;
          size_t idx = (size_t)m * 1024 + n;
          out[idx] = acc[i][j][g] + xres[idx];
        }
      }
    }
  }
}

// ------ flash attention v12: v9 structure with 128-kv SYNC UNITS ------
// (unchanged; round-8 verified)
__global__ __launch_bounds__(512, 4) void attn_kernel(const bf16* __restrict__ Qb,
                                                      const bf16* __restrict__ Kb,
                                                      const bf16* __restrict__ Vtb,
                                                      bf16* __restrict__ ctx) {
  __shared__ __align__(16) bf16 smK[2][2][64 * 64];
  __shared__ __align__(16) bf16 smV[2][2][64 * 64];
  const int bx = blockIdx.x;
  const int bh = bx & 63;
  const int i256 = (bx < 256) ? (7 - (bx >> 6)) : ((bx - 256) >> 6);
  const bf16* Qh = Qb + (size_t)bh * S_ * DH_;
  const bf16* Kh = Kb + (size_t)bh * S_ * DH_;
  const bf16* Vh = Vtb + (size_t)bh * DH_ * S_;
  bf16* Ch = ctx + (size_t)bh * S_ * DH_;
  const int tid = threadIdx.x, wave = tid >> 6, lane = tid & 63;
  const int quad = lane >> 4, r = lane & 15;
  const int r7 = r & 7;
  const int wrow = wave * 8 + (lane >> 3);         // staging row (of 64)
  const int gcol = ((lane & 7) ^ (lane >> 3)) * 8; // source-side XOR swizzle
  const f32x4 zero = {0.f, 0.f, 0.f, 0.f};
  const int xk0 = (quad ^ r7) * 8, xk1 = ((quad + 4) ^ r7) * 8;

  const int q0w = i256 * 256 + wave * 32;
  const int numkt = 4 * i256 + 4;   // always even
  const int NU = numkt >> 1;        // 128-kv units
  const int lastkt = q0w >> 6;      // per-wave: last active tile == mask tile

  bf16x8 qf[2][2];
  const float qsc = 0.125f * 1.44269504f;  // 1/sqrt(64) * log2(e)
#pragma unroll
  for (int qg = 0; qg < 2; ++qg)
#pragma unroll
    for (int hh = 0; hh < 2; ++hh) {
      bf16x8 q = *(const bf16x8*)(Qh + (size_t)(q0w + qg * 16 + r) * DH_ +
                                  hh * 32 + quad * 8);
#pragma unroll
      for (int i = 0; i < 8; ++i) q[i] = (bf16)((float)q[i] * qsc);
      qf[qg][hh] = q;
    }

  f32x4 lacc[2] = {zero, zero};
  f32x4 oacc[2][4];
#pragma unroll
  for (int qg = 0; qg < 2; ++qg)
#pragma unroll
    for (int tn = 0; tn < 4; ++tn) oacc[qg][tn] = zero;

  auto STAGE = [&](int u, int b) {  // stage both subtiles of unit u
#pragma unroll
    for (int sub = 0; sub < 2; ++sub) {
      const int kt = 2 * u + sub;
      g2lds16(Kh + (size_t)(kt * 64 + wrow) * DH_ + gcol,
              &smK[b][sub][wave * 512]);
      g2lds16(Vh + (size_t)wrow * S_ + kt * 64 + gcol,
              &smV[b][sub][wave * 512]);
    }
  };

  // prologue: unit 0 -> buffer 0, full drain (also drains Q loads)
  STAGE(0, 0);
  asm volatile("s_waitcnt vmcnt(0)\n\ts_barrier" ::: "memory");

#pragma unroll 1
  for (int u = 0; u < NU; ++u) {
    const int b = u & 1;
    if (u + 1 < NU) STAGE(u + 1, b ^ 1);  // lands in non-read buffer
#pragma unroll
    for (int sub = 0; sub < 2; ++sub) {
      const int kt = 2 * u + sub;
      if (kt <= lastkt) {  // wave not fully masked for this kv subtile
        const int kv0 = kt * 64;
        const bf16* kb = &smK[b][sub][0];
        const bf16* vb = &smV[b][sub][0];

        // S^T: s[qg][t][g] = S[kv=kv0+t*16+quad*4+g][q=q0w+qg*16+r]
        f32x4 s[2][4];
#pragma unroll
        for (int t = 0; t < 4; ++t) {
          bf16x8 kf0 = *(const bf16x8*)(kb + (t * 16 + r) * 64 + xk0);
          bf16x8 kf1 = *(const bf16x8*)(kb + (t * 16 + r) * 64 + xk1);
#pragma unroll
          for (int qg = 0; qg < 2; ++qg) {
            f32x4 z = __builtin_amdgcn_mfma_f32_16x16x32_bf16(kf0, qf[qg][0],
                                                              zero, 0, 0, 0);
            s[qg][t] = __builtin_amdgcn_mfma_f32_16x16x32_bf16(kf1, qf[qg][1],
                                                               z, 0, 0, 0);
          }
        }
        if (kt == lastkt) {  // exactly one diagonal subtile per wave
#pragma unroll
          for (int qg = 0; qg < 2; ++qg) {
            const int q = q0w + qg * 16 + r;
#pragma unroll
            for (int t = 0; t < 4; ++t) {
              const int kv = kv0 + t * 16 + quad * 4;
#pragma unroll
              for (int g = 0; g < 4; ++g)
                if (kv + g > q) s[qg][t][g] = -1e30f;
            }
          }
        }
        // P = exp2(s); l accumulate; PV via 16x16x16 MFMA (P in registers)
#pragma unroll
        for (int t = 0; t < 4; ++t) {
          bf16x4 pa[2];
#pragma unroll
          for (int qg = 0; qg < 2; ++qg) {
#pragma unroll
            for (int g = 0; g < 4; ++g)
              s[qg][t][g] = __builtin_amdgcn_exp2f(s[qg][t][g]);
            lacc[qg] += s[qg][t];
            bf16x4 pk;
#pragma unroll
            for (int g = 0; g < 4; ++g) pk[g] = (bf16)s[qg][t][g];
            pa[qg] = pk;
          }
#pragma unroll
          for (int tn = 0; tn < 4; ++tn) {
            bf16x4 vf = *(const bf16x4*)(
                vb + (tn * 16 + r) * 64 +
                ((2 * t + (quad >> 1)) ^ r7) * 8 + (quad & 1) * 4);
            oacc[0][tn] = mfma16(pa[0], vf, oacc[0][tn]);
            oacc[1][tn] = mfma16(pa[1], vf, oacc[1][tn]);
          }
        }
      }
    }
    // ONE drain per 128 kv: next unit landed (issued ~2 subtile-computes
    // ago), all LDS reads retired, all waves synced.
    asm volatile("s_waitcnt vmcnt(0) lgkmcnt(0)\n\ts_barrier" ::: "memory");
  }

  // epilogue: reduce l per q (= lane r) per qg, normalize, store
#pragma unroll
  for (int qg = 0; qg < 2; ++qg) {
    float rs = (lacc[qg][0] + lacc[qg][1]) + (lacc[qg][2] + lacc[qg][3]);
    rs += __shfl_xor(rs, 16, 64);
    rs += __shfl_xor(rs, 32, 64);
    const float inv = 1.f / rs;
    f32x4 ib;
#pragma unroll
    for (int g = 0; g < 4; ++g) ib[g] = __shfl(inv, quad * 4 + g, 64);
#pragma unroll
    for (int tn = 0; tn < 4; ++tn) {
      f32x4 ov = oacc[qg][tn] * ib;
#pragma unroll
      for (int g = 0; g < 4; ++g)
        Ch[(size_t)(q0w + qg * 16 + quad * 4 + g) * DH_ + tn * 16 + r] =
            (bf16)ov[g];
    }
  }
}

// ---------------- LayerNorm in-place on d_out ----------------
__global__ __launch_bounds__(256) void ln_kernel(float* __restrict__ out,
                                                 const float* __restrict__ gamma,
                                                 const float* __restrict__ beta) {
  __shared__ float red[8];
  size_t row = blockIdx.x;
  float* p = out + row * 1024;
  int tid = threadIdx.x;
  float4 v = ((const float4*)p)[tid];
  float s1 = v.x + v.y + v.z + v.w;
  float s2 = v.x * v.x + v.y * v.y + v.z * v.z + v.w * v.w;
#pragma unroll
  for (int o = 1; o < 64; o <<= 1) {
    s1 += __shfl_xor(s1, o, 64);
    s2 += __shfl_xor(s2, o, 64);
  }
  int wave = tid >> 6, lane = tid & 63;
  if (lane == 0) { red[wave] = s1; red[4 + wave] = s2; }
  __syncthreads();
  s1 = red[0] + red[1] + red[2] + red[3];
  s2 = red[4] + red[5] + red[6] + red[7];
  float mean = s1 * (1.f / 1024.f);
  float var = s2 * (1.f / 1024.f) - mean * mean;
  float rstd = rsqrtf(var + 1e-5f);
  float4 g = ((const float4*)gamma)[tid];
  float4 b = ((const float4*)beta)[tid];
  float4 o;
  o.x = (v.x - mean) * rstd * g.x + b.x;
  o.y = (v.y - mean) * rstd * g.y + b.y;
  o.z = (v.z - mean) * rstd * g.z + b.z;
  o.w = (v.w - mean) * rstd * g.w + b.w;
  ((float4*)p)[tid] = o;
}

extern "C" void kernel_launch(void* const* d_in, const int* in_sizes, int n_in,
                              void* d_out, int out_size, void* d_ws,
                              size_t ws_size, hipStream_t stream) {
  (void)in_sizes; (void)n_in; (void)out_size; (void)ws_size;
  const float* x  = (const float*)d_in[0];
  const float* WQ = (const float*)d_in[1];
  const float* WK = (const float*)d_in[2];
  const float* WV = (const float*)d_in[3];
  const float* WO = (const float*)d_in[4];
  const float* gamma = (const float*)d_in[5];
  const float* beta  = (const float*)d_in[6];
  float* out = (float*)d_out;

  bf16* ws = (bf16*)d_ws;
  const size_t MD = (size_t)M_ * D_;
  const size_t WW = (size_t)D_ * D_;
  bf16* xb   = ws;
  bf16* wqt  = xb + MD;
  bf16* wkt  = wqt + WW;
  bf16* wvt  = wkt + WW;
  bf16* wot  = wvt + WW;
  bf16* Qb   = wot + WW;
  bf16* Kb   = Qb + MD;
  bf16* Vtb  = Kb + MD;
  bf16* ctxb = Vtb + MD;

  constexpr int GEMM_LDS = 3 * 24 * 1024;  // 73728 B -> 2 blocks/CU
  static bool s_attr = false;
  if (!s_attr) {
    s_attr = true;
    (void)hipFuncSetAttribute(reinterpret_cast<const void*>(gemm_kernel<0>),
                              hipFuncAttributeMaxDynamicSharedMemorySize,
                              GEMM_LDS);
    (void)hipFuncSetAttribute(reinterpret_cast<const void*>(gemm_kernel<1>),
                              hipFuncAttributeMaxDynamicSharedMemorySize,
                              GEMM_LDS);
  }

  cvt_all_kernel<<<dim3(8192), dim3(256), 0, stream>>>(
      x, WQ, WK, WV, WO, xb, wqt, wkt, wvt, wot);
  gemm_kernel<0><<<dim3(768), dim3(512), GEMM_LDS, stream>>>(
      xb, wqt, wkt, wvt, Qb, Kb, Vtb, nullptr, nullptr);
  attn_kernel<<<dim3(512), dim3(512), 0, stream>>>(Qb, Kb, Vtb, ctxb);
  gemm_kernel<1><<<dim3(256), dim3(512), GEMM_LDS, stream>>>(
      ctxb, wot, nullptr, nullptr, nullptr, nullptr, nullptr, x, out);
  ln_kernel<<<dim3(8192), dim3(256), 0, stream>>>(out, gamma, beta);
}

// Round 10
// 247.360 us; speedup vs baseline: 1.0610x; 1.0054x over previous
//
#include <hip/hip_runtime.h>
#include <hip/hip_bf16.h>
#include <cstdint>
#include <cstddef>

// B=4, S=2048, D=1024, H=16, DH=64, M = B*S = 8192
#define S_ 2048
#define D_ 1024
#define H_ 16
#define DH_ 64
#define M_ 8192

using bf16 = __bf16;
using bf16x4 = __attribute__((ext_vector_type(4))) __bf16;
using bf16x8 = __attribute__((ext_vector_type(8))) __bf16;
using f32x4 = __attribute__((ext_vector_type(4))) float;
using s16x4 = __attribute__((ext_vector_type(4))) short;

__device__ __forceinline__ void g2lds16(const bf16* g, bf16* l) {
  __builtin_amdgcn_global_load_lds(
      (const __attribute__((address_space(1))) void*)g,
      (__attribute__((address_space(3))) void*)l, 16, 0, 0);
}

// 16x16x16 bf16 MFMA (used by attn PV)
__device__ __forceinline__ f32x4 mfma16(bf16x4 a, bf16x4 b, f32x4 c) {
#if __has_builtin(__builtin_amdgcn_mfma_f32_16x16x16_bf16)
  return __builtin_amdgcn_mfma_f32_16x16x16_bf16(a, b, c, 0, 0, 0);
#elif __has_builtin(__builtin_amdgcn_mfma_f32_16x16x16bf16_1k)
  return __builtin_amdgcn_mfma_f32_16x16x16bf16_1k(
      __builtin_bit_cast(s16x4, a), __builtin_bit_cast(s16x4, b), c, 0, 0, 0);
#else
  f32x4 d;
  asm("v_mfma_f32_16x16x16_bf16 %0, %1, %2, %3"
      : "=v"(d)
      : "v"(a), "v"(b), "v"(c));
  return d;
#endif
}

// ------- fused fp32->bf16 converts: x (blocks 0..4095) + 4 weights^T -------
__global__ __launch_bounds__(256) void cvt_all_kernel(
    const float* __restrict__ x, const float* __restrict__ w0,
    const float* __restrict__ w1, const float* __restrict__ w2,
    const float* __restrict__ w3, bf16* __restrict__ xb,
    bf16* __restrict__ o0, bf16* __restrict__ o1, bf16* __restrict__ o2,
    bf16* __restrict__ o3) {
  __shared__ float tile[32][33];
  int bx = blockIdx.x;
  int tid = threadIdx.x;
  if (bx < 4096) {
    size_t i = ((size_t)bx * 256 + tid) * 8;
    float4 a = *(const float4*)(x + i);
    float4 b = *(const float4*)(x + i + 4);
    bf16x8 o;
    o[0] = (bf16)a.x; o[1] = (bf16)a.y; o[2] = (bf16)a.z; o[3] = (bf16)a.w;
    o[4] = (bf16)b.x; o[5] = (bf16)b.y; o[6] = (bf16)b.z; o[7] = (bf16)b.w;
    *(bf16x8*)(xb + i) = o;
    return;
  }
  int wb = bx - 4096;
  int wsel = wb >> 10; wb &= 1023;
  const float* W; bf16* O;
  switch (wsel) {
    case 0: W = w0; O = o0; break;
    case 1: W = w1; O = o1; break;
    case 2: W = w2; O = o2; break;
    default: W = w3; O = o3; break;
  }
  int n0 = (wb & 31) * 32;
  int k0 = (wb >> 5) * 32;
#pragma unroll
  for (int i = 0; i < 4; ++i) {
    int e = tid + i * 256; int rr = e >> 5, cc = e & 31;
    tile[rr][cc] = W[(size_t)(k0 + rr) * 1024 + n0 + cc];
  }
  __syncthreads();
#pragma unroll
  for (int i = 0; i < 4; ++i) {
    int e = tid + i * 256; int rr = e >> 5, cc = e & 31;
    O[(size_t)(n0 + rr) * 1024 + k0 + cc] = (bf16)tile[cc][rr];
  }
}

// ======= GEMM256 (MODE0 / QKV): 256x256 tile, BK=64, 8-phase schedule =======
// Round-10: gemm is LDS-read-pipe-bound (MfmaUtil pinned ~32% across
// occupancy/BK variants). Per-wave 128x64 output (8x4 frags) cuts LDS
// reads/FLOP by 1.33x vs 64x64, and the 8-phase interleave (T3+T4) keeps
// counted vmcnt (4) with one barrier per phase. Half-tile slot schedule
// (derived; slot restaged exactly >=1 phase after its last reader phase):
//   ph1: stage buf1.B-h1<-t(2i+1)   ph5: stage buf0.B-h1<-t(2i+2)
//   ph2: stage buf1.A-h0<-t(2i+1)   ph6: stage buf0.A-h0<-t(2i+2)
//   ph3: stage buf1.A-h1<-t(2i+1)   ph7: stage buf0.A-h1<-t(2i+2)
//   ph4: stage buf0.B-h0<-t(2i+2)   ph8: stage buf1.B-h0<-t(2i+3)
// vmcnt(4)+barrier at ph1 and ph5 (worst-case reader: half-tile staged 2
// phases earlier; 2 half-tiles = 4 loads may stay in flight). Last
// iteration peeled: ph5 uses vmcnt(0). Staging uses the session-proven
// pre-swizzled-global-source + linear-LDS-dest pattern (0 conflicts).
__global__ __launch_bounds__(512, 2) void gemm256_kernel(
    const bf16* __restrict__ A, const bf16* __restrict__ Bt0,
    const bf16* __restrict__ Bt1, const bf16* __restrict__ Bt2,
    bf16* __restrict__ Qo, bf16* __restrict__ Ko, bf16* __restrict__ Vto) {
  extern __shared__ float4 smem4[];
  bf16* smA = (bf16*)smem4;        // [2][256][64] bf16 = 64 KB
  bf16* smB = smA + 32768;         // [2][256][64] bf16 = 64 KB

  // grid 384 = 32 Mtiles x (4 Ntiles x 3 matrices); bijective XCD swizzle
  const int wg = ((int)blockIdx.x & 7) * 48 + ((int)blockIdx.x >> 3);
  const int bn = wg % 12, bm = wg / 12;
  const int wsel = bn >> 2;
  const bf16* Bt = (wsel == 0) ? Bt0 : (wsel == 1 ? Bt1 : Bt2);
  const int n0 = (bn & 3) * 256;

  const int tid = threadIdx.x;
  const int wave = tid >> 6, lane = tid & 63;
  const int quad = lane >> 4, r = lane & 15;
  const int wr = wave >> 2, wc = wave & 3;  // 2M x 4N wave grid

  // ---- staging: each instr covers 8 rows x 64 elems (1 KB/wave-instr).
  // lane -> row lane>>3, LDS chunk lane&7, global chunk (lane&7)^(lane>>3).
  const int srow = lane >> 3;
  const int scol = ((lane & 7) ^ srow) * 8;
  const int rbase = wave * 16;  // wave's 16 rows within a 128-row half

  const int gA = bm * 256;
  const bf16 *pA00 = A + (size_t)(gA + rbase + srow) * 1024 + scol;
  const bf16 *pA01 = A + (size_t)(gA + rbase + 8 + srow) * 1024 + scol;
  const bf16 *pA10 = A + (size_t)(gA + 128 + rbase + srow) * 1024 + scol;
  const bf16 *pA11 = A + (size_t)(gA + 128 + rbase + 8 + srow) * 1024 + scol;
  const bf16 *pB00 = Bt + (size_t)(n0 + rbase + srow) * 1024 + scol;
  const bf16 *pB01 = Bt + (size_t)(n0 + rbase + 8 + srow) * 1024 + scol;
  const bf16 *pB10 = Bt + (size_t)(n0 + 128 + rbase + srow) * 1024 + scol;
  const bf16 *pB11 = Bt + (size_t)(n0 + 128 + rbase + 8 + srow) * 1024 + scol;

  auto stA_h0 = [&](bf16* b) {
    g2lds16(pA00, b + rbase * 64); pA00 += 64;
    g2lds16(pA01, b + (rbase + 8) * 64); pA01 += 64;
  };
  auto stA_h1 = [&](bf16* b) {
    g2lds16(pA10, b + (128 + rbase) * 64); pA10 += 64;
    g2lds16(pA11, b + (128 + rbase + 8) * 64); pA11 += 64;
  };
  auto stB_h0 = [&](bf16* b) {
    g2lds16(pB00, b + rbase * 64); pB00 += 64;
    g2lds16(pB01, b + (rbase + 8) * 64); pB01 += 64;
  };
  auto stB_h1 = [&](bf16* b) {
    g2lds16(pB10, b + (128 + rbase) * 64); pB10 += 64;
    g2lds16(pB11, b + (128 + rbase + 8) * 64); pB11 += 64;
  };

  f32x4 acc[8][4];
  const f32x4 zero = {0.f, 0.f, 0.f, 0.f};
#pragma unroll
  for (int i = 0; i < 8; ++i)
#pragma unroll
    for (int j = 0; j < 4; ++j) acc[i][j] = zero;

  const int x0 = (quad ^ (r & 7)) * 8;        // k-step 0 chunk
  const int x1 = ((quad + 4) ^ (r & 7)) * 8;  // k-step 1 chunk
  const int raB = (wr * 128 + r) * 64;
  const int rbB = (wc * 64 + r) * 64;

  bf16x8 af[4], bg[4];
  auto LDA = [&](const bf16* bA, int fb, int xk) {
#pragma unroll
    for (int ii = 0; ii < 4; ++ii)
      af[ii] = *(const bf16x8*)(bA + raB + (fb + ii) * 1024 + xk);
  };
  auto LDB = [&](const bf16* bB, int xk) {
#pragma unroll
    for (int j = 0; j < 4; ++j)
      bg[j] = *(const bf16x8*)(bB + rbB + j * 1024 + xk);
  };
  auto MM = [&](int base) {
    __builtin_amdgcn_s_setprio(1);
#pragma unroll
    for (int ii = 0; ii < 4; ++ii)
#pragma unroll
      for (int j = 0; j < 4; ++j)
        acc[base + ii][j] = __builtin_amdgcn_mfma_f32_16x16x32_bf16(
            af[ii], bg[j], acc[base + ii][j], 0, 0, 0);
    __builtin_amdgcn_s_setprio(0);
  };

  bf16* bA0 = smA;          bf16* bA1 = smA + 16384;
  bf16* bB0 = smB;          bf16* bB1 = smB + 16384;

  // prologue: t0 fully (oldest 8 loads) + t1.B-h0 -> steady counts from it 0
  stB_h0(bB0); stB_h1(bB0); stA_h0(bA0); stA_h1(bA0); stB_h0(bB1);

#pragma unroll 1
  for (int it = 0; it < 7; ++it) {
    // ph1 (t_even, Mfrags0-3, k0)
    asm volatile("s_waitcnt vmcnt(4)\n\ts_barrier" ::: "memory");
    LDA(bA0, 0, x0); LDB(bB0, x0);
    stB_h1(bB1);
    MM(0);
    // ph2 (Mfrags4-7, k0)
    asm volatile("s_barrier" ::: "memory");
    LDA(bA0, 4, x0);
    stA_h0(bA1);
    MM(4);
    // ph3 (Mfrags0-3, k1)
    asm volatile("s_barrier" ::: "memory");
    LDA(bA0, 0, x1); LDB(bB0, x1);
    stA_h1(bA1);
    MM(0);
    // ph4 (Mfrags4-7, k1)
    asm volatile("s_barrier" ::: "memory");
    LDA(bA0, 4, x1);
    stB_h0(bB0);
    MM(4);
    // ph5 (t_odd, Mfrags0-3, k0)
    asm volatile("s_waitcnt vmcnt(4)\n\ts_barrier" ::: "memory");
    LDA(bA1, 0, x0); LDB(bB1, x0);
    stB_h1(bB0);
    MM(0);
    // ph6
    asm volatile("s_barrier" ::: "memory");
    LDA(bA1, 4, x0);
    stA_h0(bA0);
    MM(4);
    // ph7
    asm volatile("s_barrier" ::: "memory");
    LDA(bA1, 0, x1); LDB(bB1, x1);
    stA_h1(bA0);
    MM(0);
    // ph8
    asm volatile("s_barrier" ::: "memory");
    LDA(bA1, 4, x1);
    stB_h0(bB1);
    MM(4);
  }
  // ---- peeled last iteration (tiles 14 in buf0, 15 in buf1) ----
  asm volatile("s_waitcnt vmcnt(4)\n\ts_barrier" ::: "memory");
  LDA(bA0, 0, x0); LDB(bB0, x0); stB_h1(bB1); MM(0);
  asm volatile("s_barrier" ::: "memory");
  LDA(bA0, 4, x0); stA_h0(bA1); MM(4);
  asm volatile("s_barrier" ::: "memory");
  LDA(bA0, 0, x1); LDB(bB0, x1); stA_h1(bA1); MM(0);
  asm volatile("s_barrier" ::: "memory");
  LDA(bA0, 4, x1); MM(4);
  asm volatile("s_waitcnt vmcnt(0)\n\ts_barrier" ::: "memory");
  LDA(bA1, 0, x0); LDB(bB1, x0); MM(0);
  asm volatile("s_barrier" ::: "memory");
  LDA(bA1, 4, x0); MM(4);
  asm volatile("s_barrier" ::: "memory");
  LDA(bA1, 0, x1); LDB(bB1, x1); MM(0);
  asm volatile("s_barrier" ::: "memory");
  LDA(bA1, 4, x1); MM(4);

  // ---- epilogue ----
  const int mB = bm * 256 + wr * 128 + quad * 4;  // + i*16 + g
  if (wsel < 2) {
    bf16* dst = (wsel == 0) ? Qo : Ko;
#pragma unroll
    for (int i = 0; i < 8; ++i) {
#pragma unroll
      for (int j = 0; j < 4; ++j) {
        int n = n0 + wc * 64 + j * 16 + r;
        int h = n >> 6, dh = n & 63;
#pragma unroll
        for (int g = 0; g < 4; ++g) {
          int m = mB + i * 16 + g;
          int b = m >> 11, s = m & 2047;
          dst[((size_t)(b * H_ + h) * S_ + s) * DH_ + dh] = (bf16)acc[i][j][g];
        }
      }
    }
  } else {  // V: store transposed [B,H,DH,S]
#pragma unroll
    for (int i = 0; i < 8; ++i) {
      int m = mB + i * 16;
      int b = m >> 11, s = m & 2047;
#pragma unroll
      for (int j = 0; j < 4; ++j) {
        int n = n0 + wc * 64 + j * 16 + r;
        int h = n >> 6, dh = n & 63;
        bf16x4 pk;
#pragma unroll
        for (int g = 0; g < 4; ++g) pk[g] = (bf16)acc[i][j][g];
        *(bf16x4*)(Vto + ((size_t)(b * H_ + h) * DH_ + dh) * S_ + s) = pk;
      }
    }
  }
}

// ------- GEMM v6 (kept for MODE1 / output proj): 128x256 tile, BK=32,
// 8 waves, triple-buffered, vmcnt(3) counted waits. (round-9 verified)
template <int MODE>
__global__ __launch_bounds__(512, 4) void gemm_kernel(
    const bf16* __restrict__ A,
    const bf16* __restrict__ Bt0, const bf16* __restrict__ Bt1,
    const bf16* __restrict__ Bt2,
    bf16* __restrict__ Qo, bf16* __restrict__ Ko, bf16* __restrict__ Vto,
    const float* __restrict__ xres, float* __restrict__ out) {
  extern __shared__ float4 smem4[];
  bf16* smem = (bf16*)smem4;  // 3 buffers x 12288 elems (A 4096 + B 8192)

  constexpr int NWG = (MODE == 0) ? 768 : 256;
  constexpr int CPX = NWG / 8;
  constexpr int NBN = (MODE == 0) ? 12 : 4;
  const int wg = ((int)blockIdx.x & 7) * CPX + ((int)blockIdx.x >> 3);
  const int bn = wg % NBN, bm = wg / NBN;

  const bf16* Bt;
  int n0full = 0, wsel = 0;
  if constexpr (MODE == 0) {
    wsel = bn >> 2;
    Bt = (wsel == 0) ? Bt0 : (wsel == 1 ? Bt1 : Bt2);
    n0full = (bn & 3) * 256;
  } else {
    Bt = Bt0;
    n0full = bn * 256;
  }

  const int tid = threadIdx.x;
  const int wave = tid >> 6, lane = tid & 63;
  const int quad = lane >> 4, r = lane & 15;
  const int wm = (wave >> 2) * 64, wn = (wave & 3) * 64;

  const int lrow = lane >> 2;                       // 0..15
  const int lcol = ((lane & 3) ^ (lrow & 3)) * 8;   // elements
  const int am = bm * 128 + wave * 16 + lrow;
  const bf16 *pA, *pB1, *pB2;
  if constexpr (MODE == 0) {
    pA = A + (size_t)am * 1024 + lcol;
  } else {
    pA = A + (size_t)(am >> 11) * (16 * (size_t)S_ * DH_) +
         (size_t)(am & 2047) * 64 + lcol;
  }
  const int bnr = n0full + wave * 16 + lrow;
  pB1 = Bt + (size_t)bnr * 1024 + lcol;
  pB2 = Bt + (size_t)(bnr + 128) * 1024 + lcol;
  constexpr ptrdiff_t dSum = (MODE == 0) ? 64 : (ptrdiff_t)S_ * DH_;
  ptrdiff_t dTog = 32;

  const int oA = wave * 512;
  const int oB1 = 4096 + wave * 512;
  const int oB2 = 8192 + wave * 512;

  auto stage = [&](bf16* base) {
    g2lds16(pA, base + oA);
    g2lds16(pB1, base + oB1);
    g2lds16(pB2, base + oB2);
    pA += dTog; dTog = dSum - dTog;
    pB1 += 32; pB2 += 32;
  };

  f32x4 acc[4][4];
  const f32x4 zero = {0.f, 0.f, 0.f, 0.f};
#pragma unroll
  for (int i = 0; i < 4; ++i)
#pragma unroll
    for (int j = 0; j < 4; ++j) acc[i][j] = zero;

  const int x0 = (quad ^ (r & 3)) * 8;
  const int raB = (wm + r) * 32;
  const int rbB = (wn + r) * 32;

  auto phase = [&](const bf16* buf) {
    const bf16* bA = buf;
    const bf16* bB = buf + 4096;
    bf16x8 af[4], bg[4];
#pragma unroll
    for (int i = 0; i < 4; ++i)
      af[i] = *(const bf16x8*)(bA + raB + i * 512 + x0);
#pragma unroll
    for (int j = 0; j < 4; ++j)
      bg[j] = *(const bf16x8*)(bB + rbB + j * 512 + x0);
    __builtin_amdgcn_s_setprio(1);
#pragma unroll
    for (int i = 0; i < 4; ++i)
#pragma unroll
      for (int j = 0; j < 4; ++j)
        acc[i][j] = __builtin_amdgcn_mfma_f32_16x16x32_bf16(af[i], bg[j],
                                                            acc[i][j], 0, 0, 0);
    __builtin_amdgcn_s_setprio(0);
  };

  bf16* b0 = smem;
  bf16* b1 = smem + 12288;
  bf16* b2 = smem + 24576;

  stage(b0);  // tile 0
  stage(b1);  // tile 1

#pragma unroll 1
  for (int kt = 0; kt < 30; kt += 3) {
    asm volatile("s_waitcnt vmcnt(3)\n\ts_barrier" ::: "memory");
    stage(b2);
    phase(b0);
    asm volatile("s_waitcnt vmcnt(3)\n\ts_barrier" ::: "memory");
    stage(b0);
    phase(b1);
    asm volatile("s_waitcnt vmcnt(3)\n\ts_barrier" ::: "memory");
    stage(b1);
    phase(b2);
  }
  asm volatile("s_waitcnt vmcnt(3)\n\ts_barrier" ::: "memory");
  phase(b0);                      // tile 30
  asm volatile("s_waitcnt vmcnt(0)\n\ts_barrier" ::: "memory");
  phase(b1);                      // tile 31

  const int mB = bm * 128 + wm + quad * 4;
  if constexpr (MODE == 0) {
    if (wsel < 2) {
      bf16* dst = (wsel == 0) ? Qo : Ko;
#pragma unroll
      for (int i = 0; i < 4; ++i) {
#pragma unroll
        for (int j = 0; j < 4; ++j) {
          int n = n0full + wn + j * 16 + r;
          int h = n >> 6, dh = n & 63;
#pragma unroll
          for (int g = 0; g < 4; ++g) {
            int m = mB + i * 16 + g;
            int b = m >> 11, s = m & 2047;
            dst[((size_t)(b * H_ + h) * S_ + s) * DH_ + dh] =
                (bf16)acc[i][j][g];
          }
        }
      }
    } else {
#pragma unroll
      for (int i = 0; i < 4; ++i) {
        int m = mB + i * 16;
        int b = m >> 11, s = m & 2047;
#pragma unroll
        for (int j = 0; j < 4; ++j) {
          int n = n0full + wn + j * 16 + r;
          int h = n >> 6, dh = n & 63;
          bf16x4 pk;
#pragma unroll
          for (int g = 0; g < 4; ++g) pk[g] = (bf16)acc[i][j][g];
          *(bf16x4*)(Vto + ((size_t)(b * H_ + h) * DH_ + dh) * S_ + s) = pk;
        }
      }
    }
  } else {
#pragma unroll
    for (int i = 0; i < 4; ++i) {
#pragma unroll
      for (int j = 0; j < 4; ++j) {
        int n = bn * 256 + wn + j * 16 + r;
#pragma unroll
        for (int g = 0; g < 4; ++g) {
          int m = mB + i * 16 + g;
          size_t idx = (size_t)m * 1024 + n;
          out[idx] = acc[i][j][g] + xres[idx];
        }
      }
    }
  }
}

// ------ flash attention v12: v9 structure with 128-kv SYNC UNITS ------
// (unchanged; round-8/9 verified)
__global__ __launch_bounds__(512, 4) void attn_kernel(const bf16* __restrict__ Qb,
                                                      const bf16* __restrict__ Kb,
                                                      const bf16* __restrict__ Vtb,
                                                      bf16* __restrict__ ctx) {
  __shared__ __align__(16) bf16 smK[2][2][64 * 64];
  __shared__ __align__(16) bf16 smV[2][2][64 * 64];
  const int bx = blockIdx.x;
  const int bh = bx & 63;
  const int i256 = (bx < 256) ? (7 - (bx >> 6)) : ((bx - 256) >> 6);
  const bf16* Qh = Qb + (size_t)bh * S_ * DH_;
  const bf16* Kh = Kb + (size_t)bh * S_ * DH_;
  const bf16* Vh = Vtb + (size_t)bh * DH_ * S_;
  bf16* Ch = ctx + (size_t)bh * S_ * DH_;
  const int tid = threadIdx.x, wave = tid >> 6, lane = tid & 63;
  const int quad = lane >> 4, r = lane & 15;
  const int r7 = r & 7;
  const int wrow = wave * 8 + (lane >> 3);
  const int gcol = ((lane & 7) ^ (lane >> 3)) * 8;
  const f32x4 zero = {0.f, 0.f, 0.f, 0.f};
  const int xk0 = (quad ^ r7) * 8, xk1 = ((quad + 4) ^ r7) * 8;

  const int q0w = i256 * 256 + wave * 32;
  const int numkt = 4 * i256 + 4;
  const int NU = numkt >> 1;
  const int lastkt = q0w >> 6;

  bf16x8 qf[2][2];
  const float qsc = 0.125f * 1.44269504f;
#pragma unroll
  for (int qg = 0; qg < 2; ++qg)
#pragma unroll
    for (int hh = 0; hh < 2; ++hh) {
      bf16x8 q = *(const bf16x8*)(Qh + (size_t)(q0w + qg * 16 + r) * DH_ +
                                  hh * 32 + quad * 8);
#pragma unroll
      for (int i = 0; i < 8; ++i) q[i] = (bf16)((float)q[i] * qsc);
      qf[qg][hh] = q;
    }

  f32x4 lacc[2] = {zero, zero};
  f32x4 oacc[2][4];
#pragma unroll
  for (int qg = 0; qg < 2; ++qg)
#pragma unroll
    for (int tn = 0; tn < 4; ++tn) oacc[qg][tn] = zero;

  auto STAGE = [&](int u, int b) {
#pragma unroll
    for (int sub = 0; sub < 2; ++sub) {
      const int kt = 2 * u + sub;
      g2lds16(Kh + (size_t)(kt * 64 + wrow) * DH_ + gcol,
              &smK[b][sub][wave * 512]);
      g2lds16(Vh + (size_t)wrow * S_ + kt * 64 + gcol,
              &smV[b][sub][wave * 512]);
    }
  };

  STAGE(0, 0);
  asm volatile("s_waitcnt vmcnt(0)\n\ts_barrier" ::: "memory");

#pragma unroll 1
  for (int u = 0; u < NU; ++u) {
    const int b = u & 1;
    if (u + 1 < NU) STAGE(u + 1, b ^ 1);
#pragma unroll
    for (int sub = 0; sub < 2; ++sub) {
      const int kt = 2 * u + sub;
      if (kt <= lastkt) {
        const int kv0 = kt * 64;
        const bf16* kb = &smK[b][sub][0];
        const bf16* vb = &smV[b][sub][0];

        f32x4 s[2][4];
#pragma unroll
        for (int t = 0; t < 4; ++t) {
          bf16x8 kf0 = *(const bf16x8*)(kb + (t * 16 + r) * 64 + xk0);
          bf16x8 kf1 = *(const bf16x8*)(kb + (t * 16 + r) * 64 + xk1);
#pragma unroll
          for (int qg = 0; qg < 2; ++qg) {
            f32x4 z = __builtin_amdgcn_mfma_f32_16x16x32_bf16(kf0, qf[qg][0],
                                                              zero, 0, 0, 0);
            s[qg][t] = __builtin_amdgcn_mfma_f32_16x16x32_bf16(kf1, qf[qg][1],
                                                               z, 0, 0, 0);
          }
        }
        if (kt == lastkt) {
#pragma unroll
          for (int qg = 0; qg < 2; ++qg) {
            const int q = q0w + qg * 16 + r;
#pragma unroll
            for (int t = 0; t < 4; ++t) {
              const int kv = kv0 + t * 16 + quad * 4;
#pragma unroll
              for (int g = 0; g < 4; ++g)
                if (kv + g > q) s[qg][t][g] = -1e30f;
            }
          }
        }
#pragma unroll
        for (int t = 0; t < 4; ++t) {
          bf16x4 pa[2];
#pragma unroll
          for (int qg = 0; qg < 2; ++qg) {
#pragma unroll
            for (int g = 0; g < 4; ++g)
              s[qg][t][g] = __builtin_amdgcn_exp2f(s[qg][t][g]);
            lacc[qg] += s[qg][t];
            bf16x4 pk;
#pragma unroll
            for (int g = 0; g < 4; ++g) pk[g] = (bf16)s[qg][t][g];
            pa[qg] = pk;
          }
#pragma unroll
          for (int tn = 0; tn < 4; ++tn) {
            bf16x4 vf = *(const bf16x4*)(
                vb + (tn * 16 + r) * 64 +
                ((2 * t + (quad >> 1)) ^ r7) * 8 + (quad & 1) * 4);
            oacc[0][tn] = mfma16(pa[0], vf, oacc[0][tn]);
            oacc[1][tn] = mfma16(pa[1], vf, oacc[1][tn]);
          }
        }
      }
    }
    asm volatile("s_waitcnt vmcnt(0) lgkmcnt(0)\n\ts_barrier" ::: "memory");
  }

#pragma unroll
  for (int qg = 0; qg < 2; ++qg) {
    float rs = (lacc[qg][0] + lacc[qg][1]) + (lacc[qg][2] + lacc[qg][3]);
    rs += __shfl_xor(rs, 16, 64);
    rs += __shfl_xor(rs, 32, 64);
    const float inv = 1.f / rs;
    f32x4 ib;
#pragma unroll
    for (int g = 0; g < 4; ++g) ib[g] = __shfl(inv, quad * 4 + g, 64);
#pragma unroll
    for (int tn = 0; tn < 4; ++tn) {
      f32x4 ov = oacc[qg][tn] * ib;
#pragma unroll
      for (int g = 0; g < 4; ++g)
        Ch[(size_t)(q0w + qg * 16 + quad * 4 + g) * DH_ + tn * 16 + r] =
            (bf16)ov[g];
    }
  }
}

// ---------------- LayerNorm in-place on d_out ----------------
__global__ __launch_bounds__(256) void ln_kernel(float* __restrict__ out,
                                                 const float* __restrict__ gamma,
                                                 const float* __restrict__ beta) {
  __shared__ float red[8];
  size_t row = blockIdx.x;
  float* p = out + row * 1024;
  int tid = threadIdx.x;
  float4 v = ((const float4*)p)[tid];
  float s1 = v.x + v.y + v.z + v.w;
  float s2 = v.x * v.x + v.y * v.y + v.z * v.z + v.w * v.w;
#pragma unroll
  for (int o = 1; o < 64; o <<= 1) {
    s1 += __shfl_xor(s1, o, 64);
    s2 += __shfl_xor(s2, o, 64);
  }
  int wave = tid >> 6, lane = tid & 63;
  if (lane == 0) { red[wave] = s1; red[4 + wave] = s2; }
  __syncthreads();
  s1 = red[0] + red[1] + red[2] + red[3];
  s2 = red[4] + red[5] + red[6] + red[7];
  float mean = s1 * (1.f / 1024.f);
  float var = s2 * (1.f / 1024.f) - mean * mean;
  float rstd = rsqrtf(var + 1e-5f);
  float4 g = ((const float4*)gamma)[tid];
  float4 b = ((const float4*)beta)[tid];
  float4 o;
  o.x = (v.x - mean) * rstd * g.x + b.x;
  o.y = (v.y - mean) * rstd * g.y + b.y;
  o.z = (v.z - mean) * rstd * g.z + b.z;
  o.w = (v.w - mean) * rstd * g.w + b.w;
  ((float4*)p)[tid] = o;
}

extern "C" void kernel_launch(void* const* d_in, const int* in_sizes, int n_in,
                              void* d_out, int out_size, void* d_ws,
                              size_t ws_size, hipStream_t stream) {
  (void)in_sizes; (void)n_in; (void)out_size; (void)ws_size;
  const float* x  = (const float*)d_in[0];
  const float* WQ = (const float*)d_in[1];
  const float* WK = (const float*)d_in[2];
  const float* WV = (const float*)d_in[3];
  const float* WO = (const float*)d_in[4];
  const float* gamma = (const float*)d_in[5];
  const float* beta  = (const float*)d_in[6];
  float* out = (float*)d_out;

  bf16* ws = (bf16*)d_ws;
  const size_t MD = (size_t)M_ * D_;
  const size_t WW = (size_t)D_ * D_;
  bf16* xb   = ws;
  bf16* wqt  = xb + MD;
  bf16* wkt  = wqt + WW;
  bf16* wvt  = wkt + WW;
  bf16* wot  = wvt + WW;
  bf16* Qb   = wot + WW;
  bf16* Kb   = Qb + MD;
  bf16* Vtb  = Kb + MD;
  bf16* ctxb = Vtb + MD;

  constexpr int G256_LDS = 128 * 1024;     // gemm256 double-buffered A+B
  constexpr int GEMM_LDS = 3 * 24 * 1024;  // v6 kernel (MODE1)
  static bool s_attr = false;
  if (!s_attr) {
    s_attr = true;
    (void)hipFuncSetAttribute(reinterpret_cast<const void*>(gemm256_kernel),
                              hipFuncAttributeMaxDynamicSharedMemorySize,
                              G256_LDS);
    (void)hipFuncSetAttribute(reinterpret_cast<const void*>(gemm_kernel<1>),
                              hipFuncAttributeMaxDynamicSharedMemorySize,
                              GEMM_LDS);
  }

  cvt_all_kernel<<<dim3(8192), dim3(256), 0, stream>>>(
      x, WQ, WK, WV, WO, xb, wqt, wkt, wvt, wot);
  gemm256_kernel<<<dim3(384), dim3(512), G256_LDS, stream>>>(
      xb, wqt, wkt, wvt, Qb, Kb, Vtb);
  attn_kernel<<<dim3(512), dim3(512), 0, stream>>>(Qb, Kb, Vtb, ctxb);
  gemm_kernel<1><<<dim3(256), dim3(512), GEMM_LDS, stream>>>(
      ctxb, wot, nullptr, nullptr, nullptr, nullptr, nullptr, x, out);
  ln_kernel<<<dim3(8192), dim3(256), 0, stream>>>(out, gamma, beta);
}

// Round 12
// 238.964 us; speedup vs baseline: 1.0983x; 1.0351x over previous
//
#include <hip/hip_runtime.h>
#include <hip/hip_bf16.h>
#include <cstdint>
#include <cstddef>

// B=4, S=2048, D=1024, H=16, DH=64, M = B*S = 8192
#define S_ 2048
#define D_ 1024
#define H_ 16
#define DH_ 64
#define M_ 8192

using bf16 = __bf16;
using bf16x4 = __attribute__((ext_vector_type(4))) __bf16;
using bf16x8 = __attribute__((ext_vector_type(8))) __bf16;
using f32x4 = __attribute__((ext_vector_type(4))) float;
using s16x4 = __attribute__((ext_vector_type(4))) short;

__device__ __forceinline__ void g2lds16(const bf16* g, bf16* l) {
  __builtin_amdgcn_global_load_lds(
      (const __attribute__((address_space(1))) void*)g,
      (__attribute__((address_space(3))) void*)l, 16, 0, 0);
}

// 16x16x16 bf16 MFMA (used by attn PV)
__device__ __forceinline__ f32x4 mfma16(bf16x4 a, bf16x4 b, f32x4 c) {
#if __has_builtin(__builtin_amdgcn_mfma_f32_16x16x16_bf16)
  return __builtin_amdgcn_mfma_f32_16x16x16_bf16(a, b, c, 0, 0, 0);
#elif __has_builtin(__builtin_amdgcn_mfma_f32_16x16x16bf16_1k)
  return __builtin_amdgcn_mfma_f32_16x16x16bf16_1k(
      __builtin_bit_cast(s16x4, a), __builtin_bit_cast(s16x4, b), c, 0, 0, 0);
#else
  f32x4 d;
  asm("v_mfma_f32_16x16x16_bf16 %0, %1, %2, %3"
      : "=v"(d)
      : "v"(a), "v"(b), "v"(c));
  return d;
#endif
}

// ------- fused fp32->bf16 converts: x (blocks 0..4095) + 4 weights^T -------
__global__ __launch_bounds__(256) void cvt_all_kernel(
    const float* __restrict__ x, const float* __restrict__ w0,
    const float* __restrict__ w1, const float* __restrict__ w2,
    const float* __restrict__ w3, bf16* __restrict__ xb,
    bf16* __restrict__ o0, bf16* __restrict__ o1, bf16* __restrict__ o2,
    bf16* __restrict__ o3) {
  __shared__ float tile[32][33];
  int bx = blockIdx.x;
  int tid = threadIdx.x;
  if (bx < 4096) {
    size_t i = ((size_t)bx * 256 + tid) * 8;
    float4 a = *(const float4*)(x + i);
    float4 b = *(const float4*)(x + i + 4);
    bf16x8 o;
    o[0] = (bf16)a.x; o[1] = (bf16)a.y; o[2] = (bf16)a.z; o[3] = (bf16)a.w;
    o[4] = (bf16)b.x; o[5] = (bf16)b.y; o[6] = (bf16)b.z; o[7] = (bf16)b.w;
    *(bf16x8*)(xb + i) = o;
    return;
  }
  int wb = bx - 4096;
  int wsel = wb >> 10; wb &= 1023;
  const float* W; bf16* O;
  switch (wsel) {
    case 0: W = w0; O = o0; break;
    case 1: W = w1; O = o1; break;
    case 2: W = w2; O = o2; break;
    default: W = w3; O = o3; break;
  }
  int n0 = (wb & 31) * 32;
  int k0 = (wb >> 5) * 32;
#pragma unroll
  for (int i = 0; i < 4; ++i) {
    int e = tid + i * 256; int rr = e >> 5, cc = e & 31;
    tile[rr][cc] = W[(size_t)(k0 + rr) * 1024 + n0 + cc];
  }
  __syncthreads();
#pragma unroll
  for (int i = 0; i < 4; ++i) {
    int e = tid + i * 256; int rr = e >> 5, cc = e & 31;
    O[(size_t)(n0 + rr) * 1024 + k0 + cc] = (bf16)tile[cc][rr];
  }
}

// ------- GEMM v6: 128x256 tile, BK=32, 8 waves (2M x 4N, 64x64 each),
// triple-buffered LDS 3 x 24KB -> 2 blocks/CU, vmcnt(3) counted waits,
// no mid-tile barrier. (round-9 verified)
// MODE1 (round-11/12): epilogue writes proj result as BF16 (no residual)
// to Qo -- drops the 33.5MB xres fetch and halves the write; ln adds it.
template <int MODE>
__global__ __launch_bounds__(512, 4) void gemm_kernel(
    const bf16* __restrict__ A,
    const bf16* __restrict__ Bt0, const bf16* __restrict__ Bt1,
    const bf16* __restrict__ Bt2,
    bf16* __restrict__ Qo, bf16* __restrict__ Ko, bf16* __restrict__ Vto) {
  extern __shared__ float4 smem4[];
  bf16* smem = (bf16*)smem4;  // 3 buffers x 12288 elems (A 4096 + B 8192)

  constexpr int NWG = (MODE == 0) ? 768 : 256;
  constexpr int CPX = NWG / 8;
  constexpr int NBN = (MODE == 0) ? 12 : 4;
  const int wg = ((int)blockIdx.x & 7) * CPX + ((int)blockIdx.x >> 3);
  const int bn = wg % NBN, bm = wg / NBN;

  const bf16* Bt;
  int n0full = 0, wsel = 0;
  if constexpr (MODE == 0) {
    wsel = bn >> 2;
    Bt = (wsel == 0) ? Bt0 : (wsel == 1 ? Bt1 : Bt2);
    n0full = (bn & 3) * 256;
  } else {
    Bt = Bt0;
    n0full = bn * 256;
  }

  const int tid = threadIdx.x;
  const int wave = tid >> 6, lane = tid & 63;
  const int quad = lane >> 4, r = lane & 15;
  const int wm = (wave >> 2) * 64, wn = (wave & 3) * 64;

  const int lrow = lane >> 2;                       // 0..15
  const int lcol = ((lane & 3) ^ (lrow & 3)) * 8;   // elements
  const int am = bm * 128 + wave * 16 + lrow;
  const bf16 *pA, *pB1, *pB2;
  if constexpr (MODE == 0) {
    pA = A + (size_t)am * 1024 + lcol;
  } else {
    pA = A + (size_t)(am >> 11) * (16 * (size_t)S_ * DH_) +
         (size_t)(am & 2047) * 64 + lcol;
  }
  const int bnr = n0full + wave * 16 + lrow;
  pB1 = Bt + (size_t)bnr * 1024 + lcol;
  pB2 = Bt + (size_t)(bnr + 128) * 1024 + lcol;
  constexpr ptrdiff_t dSum = (MODE == 0) ? 64 : (ptrdiff_t)S_ * DH_;
  ptrdiff_t dTog = 32;

  const int oA = wave * 512;
  const int oB1 = 4096 + wave * 512;
  const int oB2 = 8192 + wave * 512;

  auto stage = [&](bf16* base) {
    g2lds16(pA, base + oA);
    g2lds16(pB1, base + oB1);
    g2lds16(pB2, base + oB2);
    pA += dTog; dTog = dSum - dTog;
    pB1 += 32; pB2 += 32;
  };

  f32x4 acc[4][4];
  const f32x4 zero = {0.f, 0.f, 0.f, 0.f};
#pragma unroll
  for (int i = 0; i < 4; ++i)
#pragma unroll
    for (int j = 0; j < 4; ++j) acc[i][j] = zero;

  const int x0 = (quad ^ (r & 3)) * 8;
  const int raB = (wm + r) * 32;
  const int rbB = (wn + r) * 32;

  auto phase = [&](const bf16* buf) {
    const bf16* bA = buf;
    const bf16* bB = buf + 4096;
    bf16x8 af[4], bg[4];
#pragma unroll
    for (int i = 0; i < 4; ++i)
      af[i] = *(const bf16x8*)(bA + raB + i * 512 + x0);
#pragma unroll
    for (int j = 0; j < 4; ++j)
      bg[j] = *(const bf16x8*)(bB + rbB + j * 512 + x0);
    __builtin_amdgcn_s_setprio(1);
#pragma unroll
    for (int i = 0; i < 4; ++i)
#pragma unroll
      for (int j = 0; j < 4; ++j)
        acc[i][j] = __builtin_amdgcn_mfma_f32_16x16x32_bf16(af[i], bg[j],
                                                            acc[i][j], 0, 0, 0);
    __builtin_amdgcn_s_setprio(0);
  };

  bf16* b0 = smem;
  bf16* b1 = smem + 12288;
  bf16* b2 = smem + 24576;

  stage(b0);  // tile 0
  stage(b1);  // tile 1

#pragma unroll 1
  for (int kt = 0; kt < 30; kt += 3) {
    asm volatile("s_waitcnt vmcnt(3)\n\ts_barrier" ::: "memory");
    stage(b2);
    phase(b0);
    asm volatile("s_waitcnt vmcnt(3)\n\ts_barrier" ::: "memory");
    stage(b0);
    phase(b1);
    asm volatile("s_waitcnt vmcnt(3)\n\ts_barrier" ::: "memory");
    stage(b1);
    phase(b2);
  }
  asm volatile("s_waitcnt vmcnt(3)\n\ts_barrier" ::: "memory");
  phase(b0);                      // tile 30
  asm volatile("s_waitcnt vmcnt(0)\n\ts_barrier" ::: "memory");
  phase(b1);                      // tile 31

  // ---- epilogue ----
  const int mB = bm * 128 + wm + quad * 4;
  if constexpr (MODE == 0) {
    if (wsel < 2) {
      bf16* dst = (wsel == 0) ? Qo : Ko;
#pragma unroll
      for (int i = 0; i < 4; ++i) {
#pragma unroll
        for (int j = 0; j < 4; ++j) {
          int n = n0full + wn + j * 16 + r;
          int h = n >> 6, dh = n & 63;
#pragma unroll
          for (int g = 0; g < 4; ++g) {
            int m = mB + i * 16 + g;
            int b = m >> 11, s = m & 2047;
            dst[((size_t)(b * H_ + h) * S_ + s) * DH_ + dh] =
                (bf16)acc[i][j][g];
          }
        }
      }
    } else {  // V: store transposed [B,H,DH,S]
#pragma unroll
      for (int i = 0; i < 4; ++i) {
        int m = mB + i * 16;
        int b = m >> 11, s = m & 2047;
#pragma unroll
        for (int j = 0; j < 4; ++j) {
          int n = n0full + wn + j * 16 + r;
          int h = n >> 6, dh = n & 63;
          bf16x4 pk;
#pragma unroll
          for (int g = 0; g < 4; ++g) pk[g] = (bf16)acc[i][j][g];
          *(bf16x4*)(Vto + ((size_t)(b * H_ + h) * DH_ + dh) * S_ + s) = pk;
        }
      }
    }
  } else {
    // proj result as bf16, no residual (ln adds it): traffic 86->36 MB
#pragma unroll
    for (int i = 0; i < 4; ++i) {
#pragma unroll
      for (int j = 0; j < 4; ++j) {
        int n = bn * 256 + wn + j * 16 + r;
#pragma unroll
        for (int g = 0; g < 4; ++g) {
          int m = mB + i * 16 + g;
          Qo[(size_t)m * 1024 + n] = (bf16)acc[i][j][g];
        }
      }
    }
  }
}

// ------ flash attention v12: v9 structure with 128-kv SYNC UNITS ------
// (unchanged; round-8/9/10 verified)
__global__ __launch_bounds__(512, 4) void attn_kernel(const bf16* __restrict__ Qb,
                                                      const bf16* __restrict__ Kb,
                                                      const bf16* __restrict__ Vtb,
                                                      bf16* __restrict__ ctx) {
  __shared__ __align__(16) bf16 smK[2][2][64 * 64];
  __shared__ __align__(16) bf16 smV[2][2][64 * 64];
  const int bx = blockIdx.x;
  const int bh = bx & 63;
  const int i256 = (bx < 256) ? (7 - (bx >> 6)) : ((bx - 256) >> 6);
  const bf16* Qh = Qb + (size_t)bh * S_ * DH_;
  const bf16* Kh = Kb + (size_t)bh * S_ * DH_;
  const bf16* Vh = Vtb + (size_t)bh * DH_ * S_;
  bf16* Ch = ctx + (size_t)bh * S_ * DH_;
  const int tid = threadIdx.x, wave = tid >> 6, lane = tid & 63;
  const int quad = lane >> 4, r = lane & 15;
  const int r7 = r & 7;
  const int wrow = wave * 8 + (lane >> 3);
  const int gcol = ((lane & 7) ^ (lane >> 3)) * 8;
  const f32x4 zero = {0.f, 0.f, 0.f, 0.f};
  const int xk0 = (quad ^ r7) * 8, xk1 = ((quad + 4) ^ r7) * 8;

  const int q0w = i256 * 256 + wave * 32;
  const int numkt = 4 * i256 + 4;
  const int NU = numkt >> 1;
  const int lastkt = q0w >> 6;

  bf16x8 qf[2][2];
  const float qsc = 0.125f * 1.44269504f;
#pragma unroll
  for (int qg = 0; qg < 2; ++qg)
#pragma unroll
    for (int hh = 0; hh < 2; ++hh) {
      bf16x8 q = *(const bf16x8*)(Qh + (size_t)(q0w + qg * 16 + r) * DH_ +
                                  hh * 32 + quad * 8);
#pragma unroll
      for (int i = 0; i < 8; ++i) q[i] = (bf16)((float)q[i] * qsc);
      qf[qg][hh] = q;
    }

  f32x4 lacc[2] = {zero, zero};
  f32x4 oacc[2][4];
#pragma unroll
  for (int qg = 0; qg < 2; ++qg)
#pragma unroll
    for (int tn = 0; tn < 4; ++tn) oacc[qg][tn] = zero;

  auto STAGE = [&](int u, int b) {
#pragma unroll
    for (int sub = 0; sub < 2; ++sub) {
      const int kt = 2 * u + sub;
      g2lds16(Kh + (size_t)(kt * 64 + wrow) * DH_ + gcol,
              &smK[b][sub][wave * 512]);
      g2lds16(Vh + (size_t)wrow * S_ + kt * 64 + gcol,
              &smV[b][sub][wave * 512]);
    }
  };

  STAGE(0, 0);
  asm volatile("s_waitcnt vmcnt(0)\n\ts_barrier" ::: "memory");

#pragma unroll 1
  for (int u = 0; u < NU; ++u) {
    const int b = u & 1;
    if (u + 1 < NU) STAGE(u + 1, b ^ 1);
#pragma unroll
    for (int sub = 0; sub < 2; ++sub) {
      const int kt = 2 * u + sub;
      if (kt <= lastkt) {
        const int kv0 = kt * 64;
        const bf16* kb = &smK[b][sub][0];
        const bf16* vb = &smV[b][sub][0];

        f32x4 s[2][4];
#pragma unroll
        for (int t = 0; t < 4; ++t) {
          bf16x8 kf0 = *(const bf16x8*)(kb + (t * 16 + r) * 64 + xk0);
          bf16x8 kf1 = *(const bf16x8*)(kb + (t * 16 + r) * 64 + xk1);
#pragma unroll
          for (int qg = 0; qg < 2; ++qg) {
            f32x4 z = __builtin_amdgcn_mfma_f32_16x16x32_bf16(kf0, qf[qg][0],
                                                              zero, 0, 0, 0);
            s[qg][t] = __builtin_amdgcn_mfma_f32_16x16x32_bf16(kf1, qf[qg][1],
                                                               z, 0, 0, 0);
          }
        }
        if (kt == lastkt) {
#pragma unroll
          for (int qg = 0; qg < 2; ++qg) {
            const int q = q0w + qg * 16 + r;
#pragma unroll
            for (int t = 0; t < 4; ++t) {
              const int kv = kv0 + t * 16 + quad * 4;
#pragma unroll
              for (int g = 0; g < 4; ++g)
                if (kv + g > q) s[qg][t][g] = -1e30f;
            }
          }
        }
#pragma unroll
        for (int t = 0; t < 4; ++t) {
          bf16x4 pa[2];
#pragma unroll
          for (int qg = 0; qg < 2; ++qg) {
#pragma unroll
            for (int g = 0; g < 4; ++g)
              s[qg][t][g] = __builtin_amdgcn_exp2f(s[qg][t][g]);
            lacc[qg] += s[qg][t];
            bf16x4 pk;
#pragma unroll
            for (int g = 0; g < 4; ++g) pk[g] = (bf16)s[qg][t][g];
            pa[qg] = pk;
          }
#pragma unroll
          for (int tn = 0; tn < 4; ++tn) {
            bf16x4 vf = *(const bf16x4*)(
                vb + (tn * 16 + r) * 64 +
                ((2 * t + (quad >> 1)) ^ r7) * 8 + (quad & 1) * 4);
            oacc[0][tn] = mfma16(pa[0], vf, oacc[0][tn]);
            oacc[1][tn] = mfma16(pa[1], vf, oacc[1][tn]);
          }
        }
      }
    }
    asm volatile("s_waitcnt vmcnt(0) lgkmcnt(0)\n\ts_barrier" ::: "memory");
  }

#pragma unroll
  for (int qg = 0; qg < 2; ++qg) {
    float rs = (lacc[qg][0] + lacc[qg][1]) + (lacc[qg][2] + lacc[qg][3]);
    rs += __shfl_xor(rs, 16, 64);
    rs += __shfl_xor(rs, 32, 64);
    const float inv = 1.f / rs;
    f32x4 ib;
#pragma unroll
    for (int g = 0; g < 4; ++g) ib[g] = __shfl(inv, quad * 4 + g, 64);
#pragma unroll
    for (int tn = 0; tn < 4; ++tn) {
      f32x4 ov = oacc[qg][tn] * ib;
#pragma unroll
      for (int g = 0; g < 4; ++g)
        Ch[(size_t)(q0w + qg * 16 + quad * 4 + g) * DH_ + tn * 16 + r] =
            (bf16)ov[g];
    }
  }
}

// ------- LayerNorm v2: out = LN(x + proj_bf16) * gamma + beta -------
// Reads proj (bf16, from gemm<1>) + x (fp32 residual), writes fp32 out.
__global__ __launch_bounds__(256) void ln_kernel(float* __restrict__ out,
                                                 const bf16* __restrict__ pb,
                                                 const float* __restrict__ x,
                                                 const float* __restrict__ gamma,
                                                 const float* __restrict__ beta) {
  __shared__ float red[8];
  size_t row = blockIdx.x;
  int tid = threadIdx.x;
  float4 xv = ((const float4*)(x + row * 1024))[tid];
  bf16x4 pv = *(const bf16x4*)(pb + row * 1024 + tid * 4);
  float v0 = xv.x + (float)pv[0];
  float v1 = xv.y + (float)pv[1];
  float v2 = xv.z + (float)pv[2];
  float v3 = xv.w + (float)pv[3];
  float s1 = v0 + v1 + v2 + v3;
  float s2 = v0 * v0 + v1 * v1 + v2 * v2 + v3 * v3;
#pragma unroll
  for (int o = 1; o < 64; o <<= 1) {
    s1 += __shfl_xor(s1, o, 64);
    s2 += __shfl_xor(s2, o, 64);
  }
  int wave = tid >> 6, lane = tid & 63;
  if (lane == 0) { red[wave] = s1; red[4 + wave] = s2; }
  __syncthreads();
  s1 = red[0] + red[1] + red[2] + red[3];
  s2 = red[4] + red[5] + red[6] + red[7];
  float mean = s1 * (1.f / 1024.f);
  float var = s2 * (1.f / 1024.f) - mean * mean;
  float rstd = rsqrtf(var + 1e-5f);
  float4 g = ((const float4*)gamma)[tid];
  float4 b = ((const float4*)beta)[tid];
  float4 o;
  o.x = (v0 - mean) * rstd * g.x + b.x;
  o.y = (v1 - mean) * rstd * g.y + b.y;
  o.z = (v2 - mean) * rstd * g.z + b.z;
  o.w = (v3 - mean) * rstd * g.w + b.w;
  ((float4*)(out + row * 1024))[tid] = o;
}

extern "C" void kernel_launch(void* const* d_in, const int* in_sizes, int n_in,
                              void* d_out, int out_size, void* d_ws,
                              size_t ws_size, hipStream_t stream) {
  (void)in_sizes; (void)n_in; (void)out_size; (void)ws_size;
  const float* x  = (const float*)d_in[0];
  const float* WQ = (const float*)d_in[1];
  const float* WK = (const float*)d_in[2];
  const float* WV = (const float*)d_in[3];
  const float* WO = (const float*)d_in[4];
  const float* gamma = (const float*)d_in[5];
  const float* beta  = (const float*)d_in[6];
  float* out = (float*)d_out;

  bf16* ws = (bf16*)d_ws;
  const size_t MD = (size_t)M_ * D_;
  const size_t WW = (size_t)D_ * D_;
  bf16* xb   = ws;
  bf16* wqt  = xb + MD;
  bf16* wkt  = wqt + WW;
  bf16* wvt  = wkt + WW;
  bf16* wot  = wvt + WW;
  bf16* Qb   = wot + WW;
  bf16* Kb   = Qb + MD;
  bf16* Vtb  = Kb + MD;
  bf16* ctxb = Vtb + MD;
  // proj result (bf16) reuses Qb -- dead after attn_kernel.
  bf16* projb = Qb;

  constexpr int GEMM_LDS = 3 * 24 * 1024;  // 73728 B -> 2 blocks/CU
  static bool s_attr = false;
  if (!s_attr) {
    s_attr = true;
    (void)hipFuncSetAttribute(reinterpret_cast<const void*>(gemm_kernel<0>),
                              hipFuncAttributeMaxDynamicSharedMemorySize,
                              GEMM_LDS);
    (void)hipFuncSetAttribute(reinterpret_cast<const void*>(gemm_kernel<1>),
                              hipFuncAttributeMaxDynamicSharedMemorySize,
                              GEMM_LDS);
  }

  cvt_all_kernel<<<dim3(8192), dim3(256), 0, stream>>>(
      x, WQ, WK, WV, WO, xb, wqt, wkt, wvt, wot);
  gemm_kernel<0><<<dim3(768), dim3(512), GEMM_LDS, stream>>>(
      xb, wqt, wkt, wvt, Qb, Kb, Vtb);
  attn_kernel<<<dim3(512), dim3(512), 0, stream>>>(Qb, Kb, Vtb, ctxb);
  gemm_kernel<1><<<dim3(256), dim3(512), GEMM_LDS, stream>>>(
      ctxb, wot, nullptr, nullptr, projb, nullptr, nullptr);
  ln_kernel<<<dim3(8192), dim3(256), 0, stream>>>(out, projb, x, gamma, beta);
}

// Round 13
// 237.805 us; speedup vs baseline: 1.1036x; 1.0049x over previous
//
#include <hip/hip_runtime.h>
#include <hip/hip_bf16.h>
#include <cstdint>
#include <cstddef>

// B=4, S=2048, D=1024, H=16, DH=64, M = B*S = 8192
#define S_ 2048
#define D_ 1024
#define H_ 16
#define DH_ 64
#define M_ 8192

using bf16 = __bf16;
using bf16x4 = __attribute__((ext_vector_type(4))) __bf16;
using bf16x8 = __attribute__((ext_vector_type(8))) __bf16;
using f32x4 = __attribute__((ext_vector_type(4))) float;
using s16x4 = __attribute__((ext_vector_type(4))) short;

__device__ __forceinline__ void g2lds16(const bf16* g, bf16* l) {
  __builtin_amdgcn_global_load_lds(
      (const __attribute__((address_space(1))) void*)g,
      (__attribute__((address_space(3))) void*)l, 16, 0, 0);
}

// 16x16x16 bf16 MFMA (used by attn PV)
__device__ __forceinline__ f32x4 mfma16(bf16x4 a, bf16x4 b, f32x4 c) {
#if __has_builtin(__builtin_amdgcn_mfma_f32_16x16x16_bf16)
  return __builtin_amdgcn_mfma_f32_16x16x16_bf16(a, b, c, 0, 0, 0);
#elif __has_builtin(__builtin_amdgcn_mfma_f32_16x16x16bf16_1k)
  return __builtin_amdgcn_mfma_f32_16x16x16bf16_1k(
      __builtin_bit_cast(s16x4, a), __builtin_bit_cast(s16x4, b), c, 0, 0, 0);
#else
  f32x4 d;
  asm("v_mfma_f32_16x16x16_bf16 %0, %1, %2, %3"
      : "=v"(d)
      : "v"(a), "v"(b), "v"(c));
  return d;
#endif
}

// ------- fused fp32->bf16 converts: x (blocks 0..4095) + 4 weights^T -------
__global__ __launch_bounds__(256) void cvt_all_kernel(
    const float* __restrict__ x, const float* __restrict__ w0,
    const float* __restrict__ w1, const float* __restrict__ w2,
    const float* __restrict__ w3, bf16* __restrict__ xb,
    bf16* __restrict__ o0, bf16* __restrict__ o1, bf16* __restrict__ o2,
    bf16* __restrict__ o3) {
  __shared__ float tile[32][33];
  int bx = blockIdx.x;
  int tid = threadIdx.x;
  if (bx < 4096) {
    size_t i = ((size_t)bx * 256 + tid) * 8;
    float4 a = *(const float4*)(x + i);
    float4 b = *(const float4*)(x + i + 4);
    bf16x8 o;
    o[0] = (bf16)a.x; o[1] = (bf16)a.y; o[2] = (bf16)a.z; o[3] = (bf16)a.w;
    o[4] = (bf16)b.x; o[5] = (bf16)b.y; o[6] = (bf16)b.z; o[7] = (bf16)b.w;
    *(bf16x8*)(xb + i) = o;
    return;
  }
  int wb = bx - 4096;
  int wsel = wb >> 10; wb &= 1023;
  const float* W; bf16* O;
  switch (wsel) {
    case 0: W = w0; O = o0; break;
    case 1: W = w1; O = o1; break;
    case 2: W = w2; O = o2; break;
    default: W = w3; O = o3; break;
  }
  int n0 = (wb & 31) * 32;
  int k0 = (wb >> 5) * 32;
#pragma unroll
  for (int i = 0; i < 4; ++i) {
    int e = tid + i * 256; int rr = e >> 5, cc = e & 31;
    tile[rr][cc] = W[(size_t)(k0 + rr) * 1024 + n0 + cc];
  }
  __syncthreads();
#pragma unroll
  for (int i = 0; i < 4; ++i) {
    int e = tid + i * 256; int rr = e >> 5, cc = e & 31;
    O[(size_t)(n0 + rr) * 1024 + k0 + cc] = (bf16)tile[cc][rr];
  }
}

// ------- GEMM v7: 128x256 tile, BK=32, 8 waves (2M x 4N, 64x64 each),
// triple-buffered LDS 3 x 24KB -> 2 blocks/CU, vmcnt(3) counted waits,
// no mid-tile barrier. (round-9/12 verified structure)
// Round-13 change: swizzle depth 2 (row-PAIR XOR). At BK=32 a row is 64B
// (16 banks), so bank-group = (row&1)*4 + chunk; the old chunk=quad^(r&3)
// repeated every 4 lanes -> 4-way conflict (6.29M measured). New chunk =
// quad^((r>>1)&3): bank-group cycles all 8 groups over r=0..7 -> 2-way
// (free, m136), mirroring the BK=64 pattern that measured 0 conflicts.
// Staging and reader use the same XOR involution (both-sides rule).
// MODE1: epilogue writes proj as BF16 (no residual) to Qo; ln adds it.
template <int MODE>
__global__ __launch_bounds__(512, 4) void gemm_kernel(
    const bf16* __restrict__ A,
    const bf16* __restrict__ Bt0, const bf16* __restrict__ Bt1,
    const bf16* __restrict__ Bt2,
    bf16* __restrict__ Qo, bf16* __restrict__ Ko, bf16* __restrict__ Vto) {
  extern __shared__ float4 smem4[];
  bf16* smem = (bf16*)smem4;  // 3 buffers x 12288 elems (A 4096 + B 8192)

  constexpr int NWG = (MODE == 0) ? 768 : 256;
  constexpr int CPX = NWG / 8;
  constexpr int NBN = (MODE == 0) ? 12 : 4;
  const int wg = ((int)blockIdx.x & 7) * CPX + ((int)blockIdx.x >> 3);
  const int bn = wg % NBN, bm = wg / NBN;

  const bf16* Bt;
  int n0full = 0, wsel = 0;
  if constexpr (MODE == 0) {
    wsel = bn >> 2;
    Bt = (wsel == 0) ? Bt0 : (wsel == 1 ? Bt1 : Bt2);
    n0full = (bn & 3) * 256;
  } else {
    Bt = Bt0;
    n0full = bn * 256;
  }

  const int tid = threadIdx.x;
  const int wave = tid >> 6, lane = tid & 63;
  const int quad = lane >> 4, r = lane & 15;
  const int wm = (wave >> 2) * 64, wn = (wave & 3) * 64;

  const int lrow = lane >> 2;                           // 0..15
  const int lcol = ((lane & 3) ^ ((lrow >> 1) & 3)) * 8;  // row-pair swizzle
  const int am = bm * 128 + wave * 16 + lrow;
  const bf16 *pA, *pB1, *pB2;
  if constexpr (MODE == 0) {
    pA = A + (size_t)am * 1024 + lcol;
  } else {
    pA = A + (size_t)(am >> 11) * (16 * (size_t)S_ * DH_) +
         (size_t)(am & 2047) * 64 + lcol;
  }
  const int bnr = n0full + wave * 16 + lrow;
  pB1 = Bt + (size_t)bnr * 1024 + lcol;
  pB2 = Bt + (size_t)(bnr + 128) * 1024 + lcol;
  constexpr ptrdiff_t dSum = (MODE == 0) ? 64 : (ptrdiff_t)S_ * DH_;
  ptrdiff_t dTog = 32;

  const int oA = wave * 512;
  const int oB1 = 4096 + wave * 512;
  const int oB2 = 8192 + wave * 512;

  auto stage = [&](bf16* base) {
    g2lds16(pA, base + oA);
    g2lds16(pB1, base + oB1);
    g2lds16(pB2, base + oB2);
    pA += dTog; dTog = dSum - dTog;
    pB1 += 32; pB2 += 32;
  };

  f32x4 acc[4][4];
  const f32x4 zero = {0.f, 0.f, 0.f, 0.f};
#pragma unroll
  for (int i = 0; i < 4; ++i)
#pragma unroll
    for (int j = 0; j < 4; ++j) acc[i][j] = zero;

  // reader: (row>>1)&3 == (r>>1)&3 for all frag rows (offsets mult of 16)
  const int x0 = (quad ^ ((r >> 1) & 3)) * 8;
  const int raB = (wm + r) * 32;
  const int rbB = (wn + r) * 32;

  auto phase = [&](const bf16* buf) {
    const bf16* bA = buf;
    const bf16* bB = buf + 4096;
    bf16x8 af[4], bg[4];
#pragma unroll
    for (int i = 0; i < 4; ++i)
      af[i] = *(const bf16x8*)(bA + raB + i * 512 + x0);
#pragma unroll
    for (int j = 0; j < 4; ++j)
      bg[j] = *(const bf16x8*)(bB + rbB + j * 512 + x0);
    __builtin_amdgcn_s_setprio(1);
#pragma unroll
    for (int i = 0; i < 4; ++i)
#pragma unroll
      for (int j = 0; j < 4; ++j)
        acc[i][j] = __builtin_amdgcn_mfma_f32_16x16x32_bf16(af[i], bg[j],
                                                            acc[i][j], 0, 0, 0);
    __builtin_amdgcn_s_setprio(0);
  };

  bf16* b0 = smem;
  bf16* b1 = smem + 12288;
  bf16* b2 = smem + 24576;

  stage(b0);  // tile 0
  stage(b1);  // tile 1

#pragma unroll 1
  for (int kt = 0; kt < 30; kt += 3) {
    asm volatile("s_waitcnt vmcnt(3)\n\ts_barrier" ::: "memory");
    stage(b2);
    phase(b0);
    asm volatile("s_waitcnt vmcnt(3)\n\ts_barrier" ::: "memory");
    stage(b0);
    phase(b1);
    asm volatile("s_waitcnt vmcnt(3)\n\ts_barrier" ::: "memory");
    stage(b1);
    phase(b2);
  }
  asm volatile("s_waitcnt vmcnt(3)\n\ts_barrier" ::: "memory");
  phase(b0);                      // tile 30
  asm volatile("s_waitcnt vmcnt(0)\n\ts_barrier" ::: "memory");
  phase(b1);                      // tile 31

  // ---- epilogue ----
  const int mB = bm * 128 + wm + quad * 4;
  if constexpr (MODE == 0) {
    if (wsel < 2) {
      bf16* dst = (wsel == 0) ? Qo : Ko;
#pragma unroll
      for (int i = 0; i < 4; ++i) {
#pragma unroll
        for (int j = 0; j < 4; ++j) {
          int n = n0full + wn + j * 16 + r;
          int h = n >> 6, dh = n & 63;
#pragma unroll
          for (int g = 0; g < 4; ++g) {
            int m = mB + i * 16 + g;
            int b = m >> 11, s = m & 2047;
            dst[((size_t)(b * H_ + h) * S_ + s) * DH_ + dh] =
                (bf16)acc[i][j][g];
          }
        }
      }
    } else {  // V: store transposed [B,H,DH,S]
#pragma unroll
      for (int i = 0; i < 4; ++i) {
        int m = mB + i * 16;
        int b = m >> 11, s = m & 2047;
#pragma unroll
        for (int j = 0; j < 4; ++j) {
          int n = n0full + wn + j * 16 + r;
          int h = n >> 6, dh = n & 63;
          bf16x4 pk;
#pragma unroll
          for (int g = 0; g < 4; ++g) pk[g] = (bf16)acc[i][j][g];
          *(bf16x4*)(Vto + ((size_t)(b * H_ + h) * DH_ + dh) * S_ + s) = pk;
        }
      }
    }
  } else {
    // proj result as bf16, no residual (ln adds it): traffic 86->36 MB
#pragma unroll
    for (int i = 0; i < 4; ++i) {
#pragma unroll
      for (int j = 0; j < 4; ++j) {
        int n = bn * 256 + wn + j * 16 + r;
#pragma unroll
        for (int g = 0; g < 4; ++g) {
          int m = mB + i * 16 + g;
          Qo[(size_t)m * 1024 + n] = (bf16)acc[i][j][g];
        }
      }
    }
  }
}

// ------ flash attention v12: v9 structure with 128-kv SYNC UNITS ------
// (unchanged; round-8/9/10/12 verified)
__global__ __launch_bounds__(512, 4) void attn_kernel(const bf16* __restrict__ Qb,
                                                      const bf16* __restrict__ Kb,
                                                      const bf16* __restrict__ Vtb,
                                                      bf16* __restrict__ ctx) {
  __shared__ __align__(16) bf16 smK[2][2][64 * 64];
  __shared__ __align__(16) bf16 smV[2][2][64 * 64];
  const int bx = blockIdx.x;
  const int bh = bx & 63;
  const int i256 = (bx < 256) ? (7 - (bx >> 6)) : ((bx - 256) >> 6);
  const bf16* Qh = Qb + (size_t)bh * S_ * DH_;
  const bf16* Kh = Kb + (size_t)bh * S_ * DH_;
  const bf16* Vh = Vtb + (size_t)bh * DH_ * S_;
  bf16* Ch = ctx + (size_t)bh * S_ * DH_;
  const int tid = threadIdx.x, wave = tid >> 6, lane = tid & 63;
  const int quad = lane >> 4, r = lane & 15;
  const int r7 = r & 7;
  const int wrow = wave * 8 + (lane >> 3);
  const int gcol = ((lane & 7) ^ (lane >> 3)) * 8;
  const f32x4 zero = {0.f, 0.f, 0.f, 0.f};
  const int xk0 = (quad ^ r7) * 8, xk1 = ((quad + 4) ^ r7) * 8;

  const int q0w = i256 * 256 + wave * 32;
  const int numkt = 4 * i256 + 4;
  const int NU = numkt >> 1;
  const int lastkt = q0w >> 6;

  bf16x8 qf[2][2];
  const float qsc = 0.125f * 1.44269504f;
#pragma unroll
  for (int qg = 0; qg < 2; ++qg)
#pragma unroll
    for (int hh = 0; hh < 2; ++hh) {
      bf16x8 q = *(const bf16x8*)(Qh + (size_t)(q0w + qg * 16 + r) * DH_ +
                                  hh * 32 + quad * 8);
#pragma unroll
      for (int i = 0; i < 8; ++i) q[i] = (bf16)((float)q[i] * qsc);
      qf[qg][hh] = q;
    }

  f32x4 lacc[2] = {zero, zero};
  f32x4 oacc[2][4];
#pragma unroll
  for (int qg = 0; qg < 2; ++qg)
#pragma unroll
    for (int tn = 0; tn < 4; ++tn) oacc[qg][tn] = zero;

  auto STAGE = [&](int u, int b) {
#pragma unroll
    for (int sub = 0; sub < 2; ++sub) {
      const int kt = 2 * u + sub;
      g2lds16(Kh + (size_t)(kt * 64 + wrow) * DH_ + gcol,
              &smK[b][sub][wave * 512]);
      g2lds16(Vh + (size_t)wrow * S_ + kt * 64 + gcol,
              &smV[b][sub][wave * 512]);
    }
  };

  STAGE(0, 0);
  asm volatile("s_waitcnt vmcnt(0)\n\ts_barrier" ::: "memory");

#pragma unroll 1
  for (int u = 0; u < NU; ++u) {
    const int b = u & 1;
    if (u + 1 < NU) STAGE(u + 1, b ^ 1);
#pragma unroll
    for (int sub = 0; sub < 2; ++sub) {
      const int kt = 2 * u + sub;
      if (kt <= lastkt) {
        const int kv0 = kt * 64;
        const bf16* kb = &smK[b][sub][0];
        const bf16* vb = &smV[b][sub][0];

        f32x4 s[2][4];
#pragma unroll
        for (int t = 0; t < 4; ++t) {
          bf16x8 kf0 = *(const bf16x8*)(kb + (t * 16 + r) * 64 + xk0);
          bf16x8 kf1 = *(const bf16x8*)(kb + (t * 16 + r) * 64 + xk1);
#pragma unroll
          for (int qg = 0; qg < 2; ++qg) {
            f32x4 z = __builtin_amdgcn_mfma_f32_16x16x32_bf16(kf0, qf[qg][0],
                                                              zero, 0, 0, 0);
            s[qg][t] = __builtin_amdgcn_mfma_f32_16x16x32_bf16(kf1, qf[qg][1],
                                                               z, 0, 0, 0);
          }
        }
        if (kt == lastkt) {
#pragma unroll
          for (int qg = 0; qg < 2; ++qg) {
            const int q = q0w + qg * 16 + r;
#pragma unroll
            for (int t = 0; t < 4; ++t) {
              const int kv = kv0 + t * 16 + quad * 4;
#pragma unroll
              for (int g = 0; g < 4; ++g)
                if (kv + g > q) s[qg][t][g] = -1e30f;
            }
          }
        }
#pragma unroll
        for (int t = 0; t < 4; ++t) {
          bf16x4 pa[2];
#pragma unroll
          for (int qg = 0; qg < 2; ++qg) {
#pragma unroll
            for (int g = 0; g < 4; ++g)
              s[qg][t][g] = __builtin_amdgcn_exp2f(s[qg][t][g]);
            lacc[qg] += s[qg][t];
            bf16x4 pk;
#pragma unroll
            for (int g = 0; g < 4; ++g) pk[g] = (bf16)s[qg][t][g];
            pa[qg] = pk;
          }
#pragma unroll
          for (int tn = 0; tn < 4; ++tn) {
            bf16x4 vf = *(const bf16x4*)(
                vb + (tn * 16 + r) * 64 +
                ((2 * t + (quad >> 1)) ^ r7) * 8 + (quad & 1) * 4);
            oacc[0][tn] = mfma16(pa[0], vf, oacc[0][tn]);
            oacc[1][tn] = mfma16(pa[1], vf, oacc[1][tn]);
          }
        }
      }
    }
    asm volatile("s_waitcnt vmcnt(0) lgkmcnt(0)\n\ts_barrier" ::: "memory");
  }

#pragma unroll
  for (int qg = 0; qg < 2; ++qg) {
    float rs = (lacc[qg][0] + lacc[qg][1]) + (lacc[qg][2] + lacc[qg][3]);
    rs += __shfl_xor(rs, 16, 64);
    rs += __shfl_xor(rs, 32, 64);
    const float inv = 1.f / rs;
    f32x4 ib;
#pragma unroll
    for (int g = 0; g < 4; ++g) ib[g] = __shfl(inv, quad * 4 + g, 64);
#pragma unroll
    for (int tn = 0; tn < 4; ++tn) {
      f32x4 ov = oacc[qg][tn] * ib;
#pragma unroll
      for (int g = 0; g < 4; ++g)
        Ch[(size_t)(q0w + qg * 16 + quad * 4 + g) * DH_ + tn * 16 + r] =
            (bf16)ov[g];
    }
  }
}

// ------- LayerNorm v2: out = LN(x + proj_bf16) * gamma + beta -------
__global__ __launch_bounds__(256) void ln_kernel(float* __restrict__ out,
                                                 const bf16* __restrict__ pb,
                                                 const float* __restrict__ x,
                                                 const float* __restrict__ gamma,
                                                 const float* __restrict__ beta) {
  __shared__ float red[8];
  size_t row = blockIdx.x;
  int tid = threadIdx.x;
  float4 xv = ((const float4*)(x + row * 1024))[tid];
  bf16x4 pv = *(const bf16x4*)(pb + row * 1024 + tid * 4);
  float v0 = xv.x + (float)pv[0];
  float v1 = xv.y + (float)pv[1];
  float v2 = xv.z + (float)pv[2];
  float v3 = xv.w + (float)pv[3];
  float s1 = v0 + v1 + v2 + v3;
  float s2 = v0 * v0 + v1 * v1 + v2 * v2 + v3 * v3;
#pragma unroll
  for (int o = 1; o < 64; o <<= 1) {
    s1 += __shfl_xor(s1, o, 64);
    s2 += __shfl_xor(s2, o, 64);
  }
  int wave = tid >> 6, lane = tid & 63;
  if (lane == 0) { red[wave] = s1; red[4 + wave] = s2; }
  __syncthreads();
  s1 = red[0] + red[1] + red[2] + red[3];
  s2 = red[4] + red[5] + red[6] + red[7];
  float mean = s1 * (1.f / 1024.f);
  float var = s2 * (1.f / 1024.f) - mean * mean;
  float rstd = rsqrtf(var + 1e-5f);
  float4 g = ((const float4*)gamma)[tid];
  float4 b = ((const float4*)beta)[tid];
  float4 o;
  o.x = (v0 - mean) * rstd * g.x + b.x;
  o.y = (v1 - mean) * rstd * g.y + b.y;
  o.z = (v2 - mean) * rstd * g.z + b.z;
  o.w = (v3 - mean) * rstd * g.w + b.w;
  ((float4*)(out + row * 1024))[tid] = o;
}

extern "C" void kernel_launch(void* const* d_in, const int* in_sizes, int n_in,
                              void* d_out, int out_size, void* d_ws,
                              size_t ws_size, hipStream_t stream) {
  (void)in_sizes; (void)n_in; (void)out_size; (void)ws_size;
  const float* x  = (const float*)d_in[0];
  const float* WQ = (const float*)d_in[1];
  const float* WK = (const float*)d_in[2];
  const float* WV = (const float*)d_in[3];
  const float* WO = (const float*)d_in[4];
  const float* gamma = (const float*)d_in[5];
  const float* beta  = (const float*)d_in[6];
  float* out = (float*)d_out;

  bf16* ws = (bf16*)d_ws;
  const size_t MD = (size_t)M_ * D_;
  const size_t WW = (size_t)D_ * D_;
  bf16* xb   = ws;
  bf16* wqt  = xb + MD;
  bf16* wkt  = wqt + WW;
  bf16* wvt  = wkt + WW;
  bf16* wot  = wvt + WW;
  bf16* Qb   = wot + WW;
  bf16* Kb   = Qb + MD;
  bf16* Vtb  = Kb + MD;
  bf16* ctxb = Vtb + MD;
  // proj result (bf16) reuses Qb -- dead after attn_kernel.
  bf16* projb = Qb;

  constexpr int GEMM_LDS = 3 * 24 * 1024;  // 73728 B -> 2 blocks/CU
  static bool s_attr = false;
  if (!s_attr) {
    s_attr = true;
    (void)hipFuncSetAttribute(reinterpret_cast<const void*>(gemm_kernel<0>),
                              hipFuncAttributeMaxDynamicSharedMemorySize,
                              GEMM_LDS);
    (void)hipFuncSetAttribute(reinterpret_cast<const void*>(gemm_kernel<1>),
                              hipFuncAttributeMaxDynamicSharedMemorySize,
                              GEMM_LDS);
  }

  cvt_all_kernel<<<dim3(8192), dim3(256), 0, stream>>>(
      x, WQ, WK, WV, WO, xb, wqt, wkt, wvt, wot);
  gemm_kernel<0><<<dim3(768), dim3(512), GEMM_LDS, stream>>>(
      xb, wqt, wkt, wvt, Qb, Kb, Vtb);
  attn_kernel<<<dim3(512), dim3(512), 0, stream>>>(Qb, Kb, Vtb, ctxb);
  gemm_kernel<1><<<dim3(256), dim3(512), GEMM_LDS, stream>>>(
      ctxb, wot, nullptr, nullptr, projb, nullptr, nullptr);
  ln_kernel<<<dim3(8192), dim3(256), 0, stream>>>(out, projb, x, gamma, beta);
}